// Round 1
// baseline (6949.057 us; speedup 1.0000x reference)
//
#include <hip/hip_runtime.h>
#include <math.h>

#define B_   8
#define L_   1024
#define D_   768
#define R_   16
#define NSP  4
#define NREL 33

// 16-step inner FMA for 64x64 tile, 4x4 per thread (requires As, Bs, acc, tx, ty in scope)
#define TILE_FMA                                                                   \
    _Pragma("unroll")                                                              \
    for (int kk = 0; kk < 16; ++kk) {                                              \
        const float4 a4 = *reinterpret_cast<const float4*>(&As[kk][ty * 4]);       \
        const float4 b4 = *reinterpret_cast<const float4*>(&Bs[kk][tx * 4]);       \
        acc[0][0] = fmaf(a4.x, b4.x, acc[0][0]); acc[0][1] = fmaf(a4.x, b4.y, acc[0][1]); \
        acc[0][2] = fmaf(a4.x, b4.z, acc[0][2]); acc[0][3] = fmaf(a4.x, b4.w, acc[0][3]); \
        acc[1][0] = fmaf(a4.y, b4.x, acc[1][0]); acc[1][1] = fmaf(a4.y, b4.y, acc[1][1]); \
        acc[1][2] = fmaf(a4.y, b4.z, acc[1][2]); acc[1][3] = fmaf(a4.y, b4.w, acc[1][3]); \
        acc[2][0] = fmaf(a4.z, b4.x, acc[2][0]); acc[2][1] = fmaf(a4.z, b4.y, acc[2][1]); \
        acc[2][2] = fmaf(a4.z, b4.z, acc[2][2]); acc[2][3] = fmaf(a4.z, b4.w, acc[2][3]); \
        acc[3][0] = fmaf(a4.w, b4.x, acc[3][0]); acc[3][1] = fmaf(a4.w, b4.y, acc[3][1]); \
        acc[3][2] = fmaf(a4.w, b4.z, acc[3][2]); acc[3][3] = fmaf(a4.w, b4.w, acc[3][3]); \
    }

// ---------------------------------------------------------------------------
// Generic tiled GEMM: C[m][n] = act((sum_k A[m*aStride+k] * B[b*bBatchStride + k*N + n] + bias[n]) * scale)
// b = row0 / batchRows (pass batchRows = 1<<30 for non-batched B).
// M, N multiples of 64; K multiple of 16.
__global__ __launch_bounds__(256) void k_gemm(
    const float* __restrict__ A, long aStride,
    const float* __restrict__ Bm, long bBatchStride, int batchRows,
    const float* __restrict__ bias, float scale, int doRelu,
    float* __restrict__ C, long cStride, int N, int K)
{
    __shared__ __align__(16) float As[16][64];
    __shared__ __align__(16) float Bs[16][64];
    const int tid = threadIdx.x;
    const int tx = tid & 15, ty = tid >> 4;
    const long row0 = (long)blockIdx.y * 64;
    const int  col0 = blockIdx.x * 64;
    const float* Bb = Bm + (row0 / batchRows) * bBatchStride;
    const int am = tid >> 2, ak = (tid & 3) * 4;
    const int bk = tid >> 4, bn = (tid & 15) * 4;
    float acc[4][4] = {};
    for (int k0 = 0; k0 < K; k0 += 16) {
        const float4 av = *reinterpret_cast<const float4*>(A + (row0 + am) * aStride + k0 + ak);
        As[ak + 0][am] = av.x; As[ak + 1][am] = av.y; As[ak + 2][am] = av.z; As[ak + 3][am] = av.w;
        *reinterpret_cast<float4*>(&Bs[bk][bn]) =
            *reinterpret_cast<const float4*>(Bb + (long)(k0 + bk) * N + col0 + bn);
        __syncthreads();
        TILE_FMA
        __syncthreads();
    }
#pragma unroll
    for (int i = 0; i < 4; ++i) {
        const long row = row0 + ty * 4 + i;
        float4 o;
        o.x = acc[i][0]; o.y = acc[i][1]; o.z = acc[i][2]; o.w = acc[i][3];
        if (bias) {
            const int c = col0 + tx * 4;
            o.x += bias[c + 0]; o.y += bias[c + 1]; o.z += bias[c + 2]; o.w += bias[c + 3];
        }
        o.x *= scale; o.y *= scale; o.z *= scale; o.w *= scale;
        if (doRelu) {
            o.x = fmaxf(o.x, 0.f); o.y = fmaxf(o.y, 0.f);
            o.z = fmaxf(o.z, 0.f); o.w = fmaxf(o.w, 0.f);
        }
        *reinterpret_cast<float4*>(C + row * cStride + col0 + tx * 4) = o;
    }
}

// ---------------------------------------------------------------------------
// sp_emb: C = relu([A1 | A2] @ W + bias), A1/A2 [M,768], W [1536,768], C [M,768]
__global__ __launch_bounds__(256) void k_concat(
    const float* __restrict__ A1, const float* __restrict__ A2,
    const float* __restrict__ W, const float* __restrict__ bias,
    float* __restrict__ C)
{
    __shared__ __align__(16) float As[16][64];
    __shared__ __align__(16) float Bs[16][64];
    const int tid = threadIdx.x;
    const int tx = tid & 15, ty = tid >> 4;
    const long row0 = (long)blockIdx.y * 64;
    const int  col0 = blockIdx.x * 64;
    const int am = tid >> 2, ak = (tid & 3) * 4;
    const int bk = tid >> 4, bn = (tid & 15) * 4;
    float acc[4][4] = {};
    for (int k0 = 0; k0 < 2 * D_; k0 += 16) {
        const float* Asrc = (k0 < D_) ? A1 : A2;
        const int kloc = (k0 < D_) ? k0 : (k0 - D_);
        const float4 av = *reinterpret_cast<const float4*>(Asrc + (row0 + am) * (long)D_ + kloc + ak);
        As[ak + 0][am] = av.x; As[ak + 1][am] = av.y; As[ak + 2][am] = av.z; As[ak + 3][am] = av.w;
        *reinterpret_cast<float4*>(&Bs[bk][bn]) =
            *reinterpret_cast<const float4*>(W + (long)(k0 + bk) * D_ + col0 + bn);
        __syncthreads();
        TILE_FMA
        __syncthreads();
    }
#pragma unroll
    for (int i = 0; i < 4; ++i) {
        const long row = row0 + ty * 4 + i;
        const int c = col0 + tx * 4;
        float4 o;
        o.x = fmaxf(acc[i][0] + bias[c + 0], 0.f);
        o.y = fmaxf(acc[i][1] + bias[c + 1], 0.f);
        o.z = fmaxf(acc[i][2] + bias[c + 2], 0.f);
        o.w = fmaxf(acc[i][3] + bias[c + 3], 0.f);
        *reinterpret_cast<float4*>(C + row * (long)D_ + c) = o;
    }
}

// ---------------------------------------------------------------------------
// scores: out[b,q,it,k] = masked( q[b,q,:]·ks[b,k,:] + qrel[b,q,clip(k-q)±R] )
__global__ __launch_bounds__(256) void k_scores(
    const float* __restrict__ Q, const float* __restrict__ Ks,
    const float* __restrict__ qrel,
    const int* __restrict__ spw, const int* __restrict__ srcm, const int* __restrict__ attm,
    int it, float* __restrict__ outBase)
{
    __shared__ __align__(16) float As[16][64];
    __shared__ __align__(16) float Bs[16][64];
    const int tid = threadIdx.x;
    const int tx = tid & 15, ty = tid >> 4;
    const long row0 = (long)blockIdx.y * 64;   // global q row (b*L + q)
    const int  col0 = blockIdx.x * 64;         // key index within batch
    const int  b = (int)(row0 >> 10);
    const float* Kb = Ks + (long)b * L_ * D_;
    const int am = tid >> 2, ak = (tid & 3) * 4;
    float acc[4][4] = {};
    for (int d0 = 0; d0 < D_; d0 += 16) {
        const float4 av = *reinterpret_cast<const float4*>(Q + (row0 + am) * (long)D_ + d0 + ak);
        As[ak + 0][am] = av.x; As[ak + 1][am] = av.y; As[ak + 2][am] = av.z; As[ak + 3][am] = av.w;
        const float4 bv = *reinterpret_cast<const float4*>(Kb + (long)(col0 + am) * D_ + d0 + ak);
        Bs[ak + 0][am] = bv.x; Bs[ak + 1][am] = bv.y; Bs[ak + 2][am] = bv.z; Bs[ak + 3][am] = bv.w;
        __syncthreads();
        TILE_FMA
        __syncthreads();
    }
#pragma unroll
    for (int i = 0; i < 4; ++i) {
        const long qrow = row0 + ty * 4 + i;
        const int ql = (int)(qrow & (L_ - 1));
        const bool rowAct = (it < spw[qrow]) && (srcm[qrow] != 0);
        const float* qr = qrel + qrow * NREL;
        float vals[4];
#pragma unroll
        for (int j = 0; j < 4; ++j) {
            const int kc = col0 + tx * 4 + j;
            int dr = kc - ql;
            dr = dr < -R_ ? -R_ : (dr > R_ ? R_ : dr);
            const bool act = rowAct && (attm[(long)b * L_ + kc] != 0);
            vals[j] = act ? (acc[i][j] + qr[dr + R_]) : -1e18f;
        }
        float4 o; o.x = vals[0]; o.y = vals[1]; o.z = vals[2]; o.w = vals[3];
        *reinterpret_cast<float4*>(outBase + (qrow * NSP + it) * (long)L_ + col0 + tx * 4) = o;
    }
}

// ---------------------------------------------------------------------------
// qrel[m][r] = q[m,:] · rel[r,:]
__global__ __launch_bounds__(256) void k_qrel(
    const float* __restrict__ q, const float* __restrict__ rel, float* __restrict__ out)
{
    const long idx = (long)blockIdx.x * 256 + threadIdx.x;
    if (idx >= (long)B_ * L_ * NREL) return;
    const int r = (int)(idx % NREL);
    const long m = idx / NREL;
    const float4* qp = reinterpret_cast<const float4*>(q + m * D_);
    const float4* rp = reinterpret_cast<const float4*>(rel + (long)r * D_);
    float acc = 0.f;
#pragma unroll 4
    for (int d = 0; d < D_ / 4; ++d) {
        const float4 a = qp[d], bb = rp[d];
        acc += a.x * bb.x + a.y * bb.y + a.z * bb.z + a.w * bb.w;
    }
    out[idx] = acc;
}

// ---------------------------------------------------------------------------
// in-place row softmax over L=1024, rows strided by NSP*L
__global__ __launch_bounds__(256) void k_softmax(float* __restrict__ base)
{
    const long m = blockIdx.x;
    float* p = base + m * (long)(NSP * L_);
    const int t = threadIdx.x;
    float4 v = *reinterpret_cast<float4*>(p + 4 * t);
    float mx = fmaxf(fmaxf(v.x, v.y), fmaxf(v.z, v.w));
#pragma unroll
    for (int o = 32; o > 0; o >>= 1) mx = fmaxf(mx, __shfl_xor(mx, o, 64));
    __shared__ float redm[4];
    __shared__ float reds[4];
    const int wave = t >> 6;
    if ((t & 63) == 0) redm[wave] = mx;
    __syncthreads();
    mx = fmaxf(fmaxf(redm[0], redm[1]), fmaxf(redm[2], redm[3]));
    v.x = expf(v.x - mx); v.y = expf(v.y - mx); v.z = expf(v.z - mx); v.w = expf(v.w - mx);
    float s = v.x + v.y + v.z + v.w;
#pragma unroll
    for (int o = 32; o > 0; o >>= 1) s += __shfl_xor(s, o, 64);
    if ((t & 63) == 0) reds[wave] = s;
    __syncthreads();
    s = reds[0] + reds[1] + reds[2] + reds[3];
    const float inv = 1.0f / s;
    v.x *= inv; v.y *= inv; v.z *= inv; v.w *= inv;
    *reinterpret_cast<float4*>(p + 4 * t) = v;
}

// ---------------------------------------------------------------------------
__global__ __launch_bounds__(256) void k_count(const int* __restrict__ attm, float* __restrict__ counts)
{
    const int b = blockIdx.x, t = threadIdx.x;
    int c = 0;
    for (int k = t; k < L_; k += 256) c += (attm[b * L_ + k] != 0);
#pragma unroll
    for (int o = 32; o > 0; o >>= 1) c += __shfl_xor(c, o, 64);
    __shared__ int red[4];
    if ((t & 63) == 0) red[t >> 6] = c;
    __syncthreads();
    if (t == 0) counts[b] = (float)(red[0] + red[1] + red[2] + red[3]);
}

__global__ __launch_bounds__(256) void k_batchsum(
    const float* __restrict__ hid, const int* __restrict__ attm, float* __restrict__ pooled)
{
    const int b = blockIdx.x;
    const int d = blockIdx.y * 256 + threadIdx.x;
    const float* hb = hid + (long)b * L_ * D_;
    float acc = 0.f;
    for (int k = 0; k < L_; ++k)
        acc += attm[b * L_ + k] ? hb[(long)k * D_ + d] : 0.f;
    pooled[b * D_ + d] = acc;
}

// iteration-0 pooled hidc: srcm ? pooled[b]/max(count,1) : 0
__global__ __launch_bounds__(256) void k_hidc0(
    const float* __restrict__ pooled, const float* __restrict__ counts,
    const int* __restrict__ srcm, float* __restrict__ out)
{
    const long idx = (long)blockIdx.x * 256 + threadIdx.x;
    const int d = (int)(idx % D_);
    const long m = idx / D_;
    const int b = (int)(m >> 10);
    const float inv = 1.0f / fmaxf(counts[b], 1.0f);
    out[idx] = srcm[m] ? pooled[b * D_ + d] * inv : 0.0f;
}

__global__ __launch_bounds__(256) void k_masks(const int* __restrict__ spw, float* __restrict__ outM)
{
    const long idx = (long)blockIdx.x * 256 + threadIdx.x;
    const int i = (int)(idx & 3);
    const long m = idx >> 2;
    outM[idx] = (i < spw[m]) ? 1.0f : 0.0f;
}

// ---------------------------------------------------------------------------
extern "C" void kernel_launch(void* const* d_in, const int* in_sizes, int n_in,
                              void* d_out, int out_size, void* d_ws, size_t ws_size,
                              hipStream_t stream)
{
    (void)in_sizes; (void)n_in; (void)out_size; (void)ws_size;
    const float* hid     = (const float*)d_in[0];
    const float* src_hid = (const float*)d_in[1];
    const int*   spw     = (const int*)d_in[2];
    const int*   attm    = (const int*)d_in[3];
    const int*   srcm    = (const int*)d_in[4];
    const float* Wq_st = (const float*)d_in[6];
    const float* bq_st = (const float*)d_in[7];
    const float* Wk_st = (const float*)d_in[8];
    const float* bk_st = (const float*)d_in[9];
    const float* rel_st= (const float*)d_in[10];
    const float* Wq_ed = (const float*)d_in[11];
    const float* bq_ed = (const float*)d_in[12];
    const float* Wk_ed = (const float*)d_in[13];
    const float* bk_ed = (const float*)d_in[14];
    const float* rel_ed= (const float*)d_in[15];
    const float* W_sp  = (const float*)d_in[16];
    const float* b_sp  = (const float*)d_in[17];

    float* out      = (float*)d_out;
    float* outSts   = out;
    float* outEds   = out + (long)B_ * L_ * NSP * L_;
    float* outMasks = outEds + (long)B_ * L_ * NSP * L_;

    const long S = (long)B_ * L_ * D_;
    float* ws     = (float*)d_ws;
    float* kst    = ws;
    float* ked    = kst + S;
    float* h1a    = ked + S;
    float* h1b    = h1a + S;
    float* h2a    = h1b + S;
    float* h2b    = h2a + S;
    float* tmp    = h2b + S;                       // hidc / q scratch
    float* qrelb  = tmp + S;                       // B*L*33
    float* pooled = qrelb + (long)B_ * L_ * NREL;  // B*D
    float* counts = pooled + B_ * D_;              // B

    const float invs = 1.0f / sqrtf((float)D_);
    const dim3 gProj(D_ / 64, (B_ * L_) / 64);     // (12, 128)
    const dim3 gScore(L_ / 64, (B_ * L_) / 64);    // (16, 128)
    const int  qrelBlocks = (int)(((long)B_ * L_ * NREL + 255) / 256);

    k_count<<<B_, 256, 0, stream>>>(attm, counts);
    k_batchsum<<<dim3(B_, D_ / 256), 256, 0, stream>>>(hid, attm, pooled);
    k_masks<<<(B_ * L_ * NSP) / 256, 256, 0, stream>>>(spw, outMasks);

    // loop-invariant key projections
    k_gemm<<<gProj, 256, 0, stream>>>(hid, D_, Wk_st, 0, 1 << 30, bk_st, 1.f, 0, kst, D_, D_, D_);
    k_gemm<<<gProj, 256, 0, stream>>>(hid, D_, Wk_ed, 0, 1 << 30, bk_ed, 1.f, 0, ked, D_, D_, D_);

    float* h1cur = nullptr; float* h2cur = nullptr;
    float* h1nxt = h1a;     float* h2nxt = h2a;

    for (int it = 0; it < NSP; ++it) {
        if (it == 0) {
            // attn_w0 pooling collapses to per-batch masked mean; hid1==hid2 at it=0
            k_hidc0<<<(int)(S / 256), 256, 0, stream>>>(pooled, counts, srcm, tmp);
            k_concat<<<gProj, 256, 0, stream>>>(src_hid, tmp, W_sp, b_sp, h1a);
            h1cur = h1a; h2cur = h1a;
            h1nxt = h1b; h2nxt = h2a;
        } else {
            // pool st from previous iteration's softmax output (strided in d_out)
            k_gemm<<<gProj, 256, 0, stream>>>(outSts + (long)(it - 1) * L_, (long)NSP * L_,
                                              hid, (long)L_ * D_, L_,
                                              nullptr, 1.f, 0, tmp, D_, D_, L_);
            k_concat<<<gProj, 256, 0, stream>>>(h1cur, tmp, W_sp, b_sp, h1nxt);
            k_gemm<<<gProj, 256, 0, stream>>>(outEds + (long)(it - 1) * L_, (long)NSP * L_,
                                              hid, (long)L_ * D_, L_,
                                              nullptr, 1.f, 0, tmp, D_, D_, L_);
            k_concat<<<gProj, 256, 0, stream>>>(h2cur, tmp, W_sp, b_sp, h2nxt);
            h1cur = h1nxt; h2cur = h2nxt;
            h1nxt = (h1cur == h1a) ? h1b : h1a;
            h2nxt = (h2cur == h2a) ? h2b : h2a;
        }
        // ---- ST attention
        k_gemm<<<gProj, 256, 0, stream>>>(h1cur, D_, Wq_st, 0, 1 << 30, bq_st, invs, 0, tmp, D_, D_, D_);
        k_qrel<<<qrelBlocks, 256, 0, stream>>>(tmp, rel_st, qrelb);
        k_scores<<<gScore, 256, 0, stream>>>(tmp, kst, qrelb, spw, srcm, attm, it, outSts);
        k_softmax<<<B_ * L_, 256, 0, stream>>>(outSts + (long)it * L_);
        // ---- ED attention
        k_gemm<<<gProj, 256, 0, stream>>>(h2cur, D_, Wq_ed, 0, 1 << 30, bq_ed, invs, 0, tmp, D_, D_, D_);
        k_qrel<<<qrelBlocks, 256, 0, stream>>>(tmp, rel_ed, qrelb);
        k_scores<<<gScore, 256, 0, stream>>>(tmp, ked, qrelb, spw, srcm, attm, it, outEds);
        k_softmax<<<B_ * L_, 256, 0, stream>>>(outEds + (long)it * L_);
    }
}

// Round 2
// 2356.200 us; speedup vs baseline: 2.9493x; 2.9493x over previous
//
#include <hip/hip_runtime.h>
#include <math.h>

#define B_   8
#define L_   1024
#define D_   768
#define R_   16
#define NSP  4
#define NREL 33

typedef __attribute__((ext_vector_type(8))) short bf16x8;
typedef __attribute__((ext_vector_type(4))) float f32x4;

__device__ __forceinline__ unsigned short f2bf(float f) {
    unsigned int u = __float_as_uint(f);
    u += 0x7fff + ((u >> 16) & 1);          // RNE
    return (unsigned short)(u >> 16);
}
__device__ __forceinline__ float bf2f(unsigned short s) {
    return __uint_as_float(((unsigned int)s) << 16);
}

// ---------------------------------------------------------------------------
// Unified NT bf16 MFMA GEMM. A [M][K] bf16 (row stride aStride ushorts),
// optional A2 for k>=768 (concat). B [N][K] bf16 packed, batched by
// (row0/batchRows)*bBatch. 128x128 tile, BK=32, 4 waves, 64x64 per wave.
// MODE 0: C bf16 [M][cStride], value = (acc+bias[col])*scale, optional relu.
// MODE 1: scores epilogue -> fp32 out[(m*NSP+it)*L + col] with rel+mask.
template<int MODE>
__global__ __launch_bounds__(256) void k_mfma(
    const unsigned short* __restrict__ A, long aStride,
    const unsigned short* __restrict__ A2,
    const unsigned short* __restrict__ Bn, long bBatch, int batchRows,
    const float* __restrict__ bias, float scale, int doRelu,
    void* __restrict__ Cout, long cStride, int N, int K,
    const float* __restrict__ qrel, const int* __restrict__ spw,
    const int* __restrict__ srcm, const int* __restrict__ attm, int it)
{
    __shared__ unsigned short As[128][40];   // 32 data + 8 pad (80B rows)
    __shared__ unsigned short Bs[128][40];
    const int tid  = threadIdx.x;
    const int lane = tid & 63;
    const int wave = tid >> 6;
    const int wr = wave >> 1, wc = wave & 1;
    const int lq = lane >> 4, lr = lane & 15;
    const long row0 = (long)blockIdx.y * 128;
    const int  col0 = blockIdx.x * 128;
    const unsigned short* Bb = Bn + (row0 / batchRows) * bBatch;

    const int r0s = tid >> 2;          // staging row (chunk t)
    const int s0  = (tid & 3) * 8;     // staging col (ushorts)

    f32x4 acc[4][4];
#pragma unroll
    for (int m = 0; m < 4; ++m)
#pragma unroll
        for (int n = 0; n < 4; ++n) acc[m][n] = (f32x4)0.f;

    for (int k0 = 0; k0 < K; k0 += 32) {
        const unsigned short* Ak; int kk;
        if (A2 != nullptr && k0 >= D_) { Ak = A2; kk = k0 - D_; } else { Ak = A; kk = k0; }
        const int4 va0 = *(const int4*)(Ak + (row0 + r0s) * aStride + kk + s0);
        const int4 va1 = *(const int4*)(Ak + (row0 + r0s + 64) * aStride + kk + s0);
        const int4 vb0 = *(const int4*)(Bb + (long)(col0 + r0s) * K + k0 + s0);
        const int4 vb1 = *(const int4*)(Bb + (long)(col0 + r0s + 64) * K + k0 + s0);
        __syncthreads();
        *(int4*)&As[r0s][s0]      = va0;
        *(int4*)&As[r0s + 64][s0] = va1;
        *(int4*)&Bs[r0s][s0]      = vb0;
        *(int4*)&Bs[r0s + 64][s0] = vb1;
        __syncthreads();
        bf16x8 af[4], bfr[4];
#pragma unroll
        for (int m = 0; m < 4; ++m) af[m]  = *(const bf16x8*)&As[wr * 64 + m * 16 + lr][lq * 8];
#pragma unroll
        for (int n = 0; n < 4; ++n) bfr[n] = *(const bf16x8*)&Bs[wc * 64 + n * 16 + lr][lq * 8];
#pragma unroll
        for (int m = 0; m < 4; ++m)
#pragma unroll
            for (int n = 0; n < 4; ++n)
                acc[m][n] = __builtin_amdgcn_mfma_f32_16x16x32_bf16(af[m], bfr[n], acc[m][n], 0, 0, 0);
    }

    if (MODE == 0) {
        unsigned short* C = (unsigned short*)Cout;
#pragma unroll
        for (int n = 0; n < 4; ++n) {
            const int col = col0 + wc * 64 + n * 16 + lr;
            const float bc = bias ? bias[col] : 0.f;
#pragma unroll
            for (int m = 0; m < 4; ++m) {
#pragma unroll
                for (int r = 0; r < 4; ++r) {
                    const long row = row0 + wr * 64 + m * 16 + lq * 4 + r;
                    float v = (acc[m][n][r] + bc) * scale;
                    if (doRelu) v = fmaxf(v, 0.f);
                    C[row * cStride + col] = f2bf(v);
                }
            }
        }
    } else {
        float* C = (float*)Cout;
        const int b = (int)(row0 >> 10);
        int amv[4];
#pragma unroll
        for (int n = 0; n < 4; ++n)
            amv[n] = attm[b * L_ + col0 + wc * 64 + n * 16 + lr];
#pragma unroll
        for (int m = 0; m < 4; ++m) {
#pragma unroll
            for (int r = 0; r < 4; ++r) {
                const long mg = row0 + wr * 64 + m * 16 + lq * 4 + r;
                const int ql = (int)(mg & (L_ - 1));
                const bool rowAct = (it < spw[mg]) && (srcm[mg] != 0);
                const float* qr = qrel + mg * NREL;
#pragma unroll
                for (int n = 0; n < 4; ++n) {
                    const int col = col0 + wc * 64 + n * 16 + lr;
                    int dr = col - ql; dr = dr < -R_ ? -R_ : (dr > R_ ? R_ : dr);
                    const float v = (rowAct && amv[n]) ? (acc[m][n][r] + qr[dr + R_]) : -1e18f;
                    C[(mg * NSP + it) * L_ + col] = v;
                }
            }
        }
    }
}

// ---------------------------------------------------------------------------
// transpose + bf16 convert: out[n][k] = bf16(in[k][n]) per batch z
__global__ __launch_bounds__(256) void k_transpose(
    const float* __restrict__ in, long inBatch,
    unsigned short* __restrict__ out, long outBatch, int rows, int cols)
{
    __shared__ float t[32][33];
    const int z = blockIdx.z;
    const float* I = in + (long)z * inBatch;
    unsigned short* O = out + (long)z * outBatch;
    const int c0 = blockIdx.x * 32, r0 = blockIdx.y * 32;
    const int tx = threadIdx.x & 31, ty = threadIdx.x >> 5;
#pragma unroll
    for (int i = 0; i < 32; i += 8)
        t[ty + i][tx] = I[(long)(r0 + ty + i) * cols + c0 + tx];
    __syncthreads();
#pragma unroll
    for (int i = 0; i < 32; i += 8)
        O[(long)(c0 + ty + i) * rows + r0 + tx] = f2bf(t[tx][ty + i]);
}

// fp32 -> bf16 elementwise (n4 float4 groups)
__global__ __launch_bounds__(256) void k_cvt(
    const float* __restrict__ in, unsigned short* __restrict__ out, long n4)
{
    const long i = (long)blockIdx.x * 256 + threadIdx.x;
    if (i >= n4) return;
    const float4 v = ((const float4*)in)[i];
    ushort4 o; o.x = f2bf(v.x); o.y = f2bf(v.y); o.z = f2bf(v.z); o.w = f2bf(v.w);
    ((ushort4*)out)[i] = o;
}

// ---------------------------------------------------------------------------
// qrel[m][r] = q[m,:] . rel[r,:]   (q bf16, rel fp32)
__global__ __launch_bounds__(256) void k_qrel(
    const unsigned short* __restrict__ q, const float* __restrict__ rel,
    float* __restrict__ out)
{
    const long idx = (long)blockIdx.x * 256 + threadIdx.x;
    if (idx >= (long)B_ * L_ * NREL) return;
    const int r = (int)(idx % NREL);
    const long m = idx / NREL;
    const unsigned short* qp = q + m * D_;
    const float* rp = rel + (long)r * D_;
    float acc = 0.f;
    for (int d = 0; d < D_; d += 8) {
        const int4 u = *(const int4*)(qp + d);
        const float4 ra = *(const float4*)(rp + d);
        const float4 rb = *(const float4*)(rp + d + 4);
        acc += bf2f((unsigned short)(u.x & 0xffff)) * ra.x
             + bf2f((unsigned short)((unsigned)u.x >> 16)) * ra.y
             + bf2f((unsigned short)(u.y & 0xffff)) * ra.z
             + bf2f((unsigned short)((unsigned)u.y >> 16)) * ra.w
             + bf2f((unsigned short)(u.z & 0xffff)) * rb.x
             + bf2f((unsigned short)((unsigned)u.z >> 16)) * rb.y
             + bf2f((unsigned short)(u.w & 0xffff)) * rb.z
             + bf2f((unsigned short)((unsigned)u.w >> 16)) * rb.w;
    }
    out[idx] = acc;
}

// ---------------------------------------------------------------------------
// in-place row softmax over L=1024 (rows strided NSP*L) + bf16 copy of row
__global__ __launch_bounds__(256) void k_softmax(
    float* __restrict__ base, unsigned short* __restrict__ bfout)
{
    const long m = blockIdx.x;
    float* p = base + m * (long)(NSP * L_);
    const int t = threadIdx.x;
    float4 v = *reinterpret_cast<float4*>(p + 4 * t);
    float mx = fmaxf(fmaxf(v.x, v.y), fmaxf(v.z, v.w));
#pragma unroll
    for (int o = 32; o > 0; o >>= 1) mx = fmaxf(mx, __shfl_xor(mx, o, 64));
    __shared__ float redm[4];
    __shared__ float reds[4];
    const int wave = t >> 6;
    if ((t & 63) == 0) redm[wave] = mx;
    __syncthreads();
    mx = fmaxf(fmaxf(redm[0], redm[1]), fmaxf(redm[2], redm[3]));
    v.x = expf(v.x - mx); v.y = expf(v.y - mx); v.z = expf(v.z - mx); v.w = expf(v.w - mx);
    float s = v.x + v.y + v.z + v.w;
#pragma unroll
    for (int o = 32; o > 0; o >>= 1) s += __shfl_xor(s, o, 64);
    if ((t & 63) == 0) reds[wave] = s;
    __syncthreads();
    s = reds[0] + reds[1] + reds[2] + reds[3];
    const float inv = 1.0f / s;
    v.x *= inv; v.y *= inv; v.z *= inv; v.w *= inv;
    *reinterpret_cast<float4*>(p + 4 * t) = v;
    ushort4 o; o.x = f2bf(v.x); o.y = f2bf(v.y); o.z = f2bf(v.z); o.w = f2bf(v.w);
    *(ushort4*)&bfout[m * (long)L_ + 4 * t] = o;
}

// ---------------------------------------------------------------------------
__global__ __launch_bounds__(256) void k_count(const int* __restrict__ attm, float* __restrict__ counts)
{
    const int b = blockIdx.x, t = threadIdx.x;
    int c = 0;
    for (int k = t; k < L_; k += 256) c += (attm[b * L_ + k] != 0);
#pragma unroll
    for (int o = 32; o > 0; o >>= 1) c += __shfl_xor(c, o, 64);
    __shared__ int red[4];
    if ((t & 63) == 0) red[t >> 6] = c;
    __syncthreads();
    if (t == 0) counts[b] = (float)(red[0] + red[1] + red[2] + red[3]);
}

__global__ __launch_bounds__(256) void k_batchsum(
    const float* __restrict__ hid, const int* __restrict__ attm, float* __restrict__ pooled)
{
    const int b = blockIdx.x;
    const int d = blockIdx.y * 256 + threadIdx.x;
    const float* hb = hid + (long)b * L_ * D_;
    float acc = 0.f;
    for (int k = 0; k < L_; ++k)
        acc += attm[b * L_ + k] ? hb[(long)k * D_ + d] : 0.f;
    pooled[b * D_ + d] = acc;
}

// iteration-0 pooled hidc (bf16): srcm ? pooled[b]/max(count,1) : 0
__global__ __launch_bounds__(256) void k_hidc0(
    const float* __restrict__ pooled, const float* __restrict__ counts,
    const int* __restrict__ srcm, unsigned short* __restrict__ out)
{
    const long idx = (long)blockIdx.x * 256 + threadIdx.x;
    const int d = (int)(idx % D_);
    const long m = idx / D_;
    const int b = (int)(m >> 10);
    const float inv = 1.0f / fmaxf(counts[b], 1.0f);
    out[idx] = f2bf(srcm[m] ? pooled[b * D_ + d] * inv : 0.0f);
}

__global__ __launch_bounds__(256) void k_masks(const int* __restrict__ spw, float* __restrict__ outM)
{
    const long idx = (long)blockIdx.x * 256 + threadIdx.x;
    const int i = (int)(idx & 3);
    const long m = idx >> 2;
    outM[idx] = (i < spw[m]) ? 1.0f : 0.0f;
}

// ---------------------------------------------------------------------------
extern "C" void kernel_launch(void* const* d_in, const int* in_sizes, int n_in,
                              void* d_out, int out_size, void* d_ws, size_t ws_size,
                              hipStream_t stream)
{
    (void)in_sizes; (void)n_in; (void)out_size; (void)ws_size;
    const float* hid     = (const float*)d_in[0];
    const float* src_hid = (const float*)d_in[1];
    const int*   spw     = (const int*)d_in[2];
    const int*   attm    = (const int*)d_in[3];
    const int*   srcm    = (const int*)d_in[4];
    const float* Wq_st = (const float*)d_in[6];
    const float* bq_st = (const float*)d_in[7];
    const float* Wk_st = (const float*)d_in[8];
    const float* bk_st = (const float*)d_in[9];
    const float* rel_st= (const float*)d_in[10];
    const float* Wq_ed = (const float*)d_in[11];
    const float* bq_ed = (const float*)d_in[12];
    const float* Wk_ed = (const float*)d_in[13];
    const float* bk_ed = (const float*)d_in[14];
    const float* rel_ed= (const float*)d_in[15];
    const float* W_sp  = (const float*)d_in[16];
    const float* b_sp  = (const float*)d_in[17];

    float* out      = (float*)d_out;
    float* outSts   = out;
    float* outEds   = out + (long)B_ * L_ * NSP * L_;
    float* outMasks = outEds + (long)B_ * L_ * NSP * L_;

    const long S = (long)B_ * L_ * D_;
    char* wsB = (char*)d_ws;
    auto take = [&](size_t bytes) -> char* {
        char* p = wsB; wsB += (bytes + 255) & ~(size_t)255; return p;
    };
    unsigned short* hid_bf  = (unsigned short*)take(S * 2);
    unsigned short* src_bf  = (unsigned short*)take(S * 2);
    unsigned short* hidT    = (unsigned short*)take(S * 2);   // [B][D][L]
    unsigned short* kst     = (unsigned short*)take(S * 2);
    unsigned short* ked     = (unsigned short*)take(S * 2);
    unsigned short* h1a     = (unsigned short*)take(S * 2);
    unsigned short* h1b     = (unsigned short*)take(S * 2);
    unsigned short* h2a     = (unsigned short*)take(S * 2);
    unsigned short* h2b     = (unsigned short*)take(S * 2);
    unsigned short* tmpQ    = (unsigned short*)take(S * 2);
    unsigned short* WqTst   = (unsigned short*)take((long)D_ * D_ * 2);
    unsigned short* WkTst   = (unsigned short*)take((long)D_ * D_ * 2);
    unsigned short* WqTed   = (unsigned short*)take((long)D_ * D_ * 2);
    unsigned short* WkTed   = (unsigned short*)take((long)D_ * D_ * 2);
    unsigned short* WspT    = (unsigned short*)take((long)2 * D_ * D_ * 2);
    unsigned short* attn_st = (unsigned short*)take((long)B_ * L_ * L_ * 2);
    unsigned short* attn_ed = (unsigned short*)take((long)B_ * L_ * L_ * 2);
    float* qrelb  = (float*)take((long)B_ * L_ * NREL * 4);
    float* pooled = (float*)take((long)B_ * D_ * 4);
    float* counts = (float*)take(256);

    const float invs = 1.0f / sqrtf((float)D_);
    const dim3 gP(D_ / 128, (B_ * L_) / 128);   // (6, 64)
    const dim3 gS(L_ / 128, (B_ * L_) / 128);   // (8, 64)
    const int  qrelBlocks = (int)(((long)B_ * L_ * NREL + 255) / 256);
    const long NOB = 1L << 30;

    // ---- one-time prep
    k_cvt<<<(int)(S / 4 / 256), 256, 0, stream>>>(hid, hid_bf, S / 4);
    k_cvt<<<(int)(S / 4 / 256), 256, 0, stream>>>(src_hid, src_bf, S / 4);
    k_transpose<<<dim3(D_ / 32, D_ / 32), 256, 0, stream>>>(Wq_st, 0, WqTst, 0, D_, D_);
    k_transpose<<<dim3(D_ / 32, D_ / 32), 256, 0, stream>>>(Wk_st, 0, WkTst, 0, D_, D_);
    k_transpose<<<dim3(D_ / 32, D_ / 32), 256, 0, stream>>>(Wq_ed, 0, WqTed, 0, D_, D_);
    k_transpose<<<dim3(D_ / 32, D_ / 32), 256, 0, stream>>>(Wk_ed, 0, WkTed, 0, D_, D_);
    k_transpose<<<dim3(D_ / 32, 2 * D_ / 32), 256, 0, stream>>>(W_sp, 0, WspT, 0, 2 * D_, D_);
    k_transpose<<<dim3(D_ / 32, L_ / 32, B_), 256, 0, stream>>>(hid, (long)L_ * D_, hidT, (long)D_ * L_, L_, D_);
    k_count<<<B_, 256, 0, stream>>>(attm, counts);
    k_batchsum<<<dim3(B_, D_ / 256), 256, 0, stream>>>(hid, attm, pooled);
    k_masks<<<(B_ * L_ * NSP) / 256, 256, 0, stream>>>(spw, outMasks);

    // loop-invariant key projections
    k_mfma<0><<<gP, 256, 0, stream>>>(hid_bf, D_, nullptr, WkTst, 0, (int)NOB, bk_st, 1.f, 0,
                                      kst, D_, D_, D_, nullptr, nullptr, nullptr, nullptr, 0);
    k_mfma<0><<<gP, 256, 0, stream>>>(hid_bf, D_, nullptr, WkTed, 0, (int)NOB, bk_ed, 1.f, 0,
                                      ked, D_, D_, D_, nullptr, nullptr, nullptr, nullptr, 0);

    unsigned short* h1cur = nullptr; unsigned short* h2cur = nullptr;
    unsigned short* h1nxt = h1a;     unsigned short* h2nxt = h2a;

    for (int it = 0; it < NSP; ++it) {
        if (it == 0) {
            k_hidc0<<<(int)(S / 256), 256, 0, stream>>>(pooled, counts, srcm, tmpQ);
            k_mfma<0><<<gP, 256, 0, stream>>>(src_bf, D_, tmpQ, WspT, 0, (int)NOB, b_sp, 1.f, 1,
                                              h1a, D_, D_, 2 * D_, nullptr, nullptr, nullptr, nullptr, 0);
            h1cur = h1a; h2cur = h1a;
            h1nxt = h1b; h2nxt = h2a;
        } else {
            k_mfma<0><<<gP, 256, 0, stream>>>(attn_st, L_, nullptr, hidT, (long)D_ * L_, L_,
                                              nullptr, 1.f, 0, tmpQ, D_, D_, L_,
                                              nullptr, nullptr, nullptr, nullptr, 0);
            k_mfma<0><<<gP, 256, 0, stream>>>(h1cur, D_, tmpQ, WspT, 0, (int)NOB, b_sp, 1.f, 1,
                                              h1nxt, D_, D_, 2 * D_, nullptr, nullptr, nullptr, nullptr, 0);
            k_mfma<0><<<gP, 256, 0, stream>>>(attn_ed, L_, nullptr, hidT, (long)D_ * L_, L_,
                                              nullptr, 1.f, 0, tmpQ, D_, D_, L_,
                                              nullptr, nullptr, nullptr, nullptr, 0);
            k_mfma<0><<<gP, 256, 0, stream>>>(h2cur, D_, tmpQ, WspT, 0, (int)NOB, b_sp, 1.f, 1,
                                              h2nxt, D_, D_, 2 * D_, nullptr, nullptr, nullptr, nullptr, 0);
            h1cur = h1nxt; h2cur = h2nxt;
            h1nxt = (h1cur == h1a) ? h1b : h1a;
            h2nxt = (h2cur == h2a) ? h2b : h2a;
        }
        // ---- ST attention
        k_mfma<0><<<gP, 256, 0, stream>>>(h1cur, D_, nullptr, WqTst, 0, (int)NOB, bq_st, invs, 0,
                                          tmpQ, D_, D_, D_, nullptr, nullptr, nullptr, nullptr, 0);
        k_qrel<<<qrelBlocks, 256, 0, stream>>>(tmpQ, rel_st, qrelb);
        k_mfma<1><<<gS, 256, 0, stream>>>(tmpQ, D_, nullptr, kst, (long)L_ * D_, L_,
                                          nullptr, 1.f, 0, outSts, 0, L_, D_,
                                          qrelb, spw, srcm, attm, it);
        k_softmax<<<B_ * L_, 256, 0, stream>>>(outSts + (long)it * L_, attn_st);
        // ---- ED attention
        k_mfma<0><<<gP, 256, 0, stream>>>(h2cur, D_, nullptr, WqTed, 0, (int)NOB, bq_ed, invs, 0,
                                          tmpQ, D_, D_, D_, nullptr, nullptr, nullptr, nullptr, 0);
        k_qrel<<<qrelBlocks, 256, 0, stream>>>(tmpQ, rel_ed, qrelb);
        k_mfma<1><<<gS, 256, 0, stream>>>(tmpQ, D_, nullptr, ked, (long)L_ * D_, L_,
                                          nullptr, 1.f, 0, outEds, 0, L_, D_,
                                          qrelb, spw, srcm, attm, it);
        k_softmax<<<B_ * L_, 256, 0, stream>>>(outEds + (long)it * L_, attn_ed);
    }
}

// Round 3
// 1403.632 us; speedup vs baseline: 4.9508x; 1.6786x over previous
//
#include <hip/hip_runtime.h>
#include <math.h>

#define B_   8
#define L_   1024
#define D_   768
#define R_   16
#define NSP  4
#define NREL 33

typedef __attribute__((ext_vector_type(8))) short bf16x8;
typedef __attribute__((ext_vector_type(4))) float f32x4;
typedef __attribute__((address_space(1))) const void gv_t;
typedef __attribute__((address_space(3))) void sv_t;

__device__ __forceinline__ unsigned short f2bf(float f) {
    unsigned int u = __float_as_uint(f);
    u += 0x7fff + ((u >> 16) & 1);          // RNE
    return (unsigned short)(u >> 16);
}
__device__ __forceinline__ float bf2f(unsigned short s) {
    return __uint_as_float(((unsigned int)s) << 16);
}

// ---------------------------------------------------------------------------
// NT bf16 MFMA GEMM, 128x128 tile, BK=32, 4 waves (2x2), 64x64/wave.
// Staging: global_load_lds width=16 into linear LDS, double-buffered,
// 2-phase schedule (stage t+1 -> ds_read/MFMA t -> vmcnt(0)+barrier).
// MODE 0: bf16 out = relu?((acc + bias[col] + addend[row,col]) * scale)
// MODE 1: scores epilogue -> fp32 out[(m*NSP+it)*L + col] with rel+mask
// MODE 2: fp32 out[row*cStride+col] for col < Nvalid (qrel)
template<int MODE>
__global__ __launch_bounds__(256) void k_mfma(
    const unsigned short* __restrict__ A, long aStride,
    const unsigned short* __restrict__ Bn, long bStride, long bBatch, int batchRows,
    const float* __restrict__ bias, const unsigned short* __restrict__ addend,
    float scale, int doRelu,
    void* __restrict__ Cout, long cStride, int K,
    const float* __restrict__ qrel, const int* __restrict__ spw,
    const int* __restrict__ srcm, const int* __restrict__ attm, int it, int Nvalid)
{
    __shared__ unsigned short As[2][128 * 32];
    __shared__ unsigned short Bs[2][128 * 32];
    const int tid  = threadIdx.x;
    const int lane = tid & 63;
    const int wave = tid >> 6;
    const int wr = wave >> 1, wc = wave & 1;
    const int lq = lane >> 4, lr = lane & 15;
    const long row0 = (long)blockIdx.y * 128;
    const int  col0 = blockIdx.x * 128;
    const unsigned short* Bb = Bn + (row0 / batchRows) * bBatch;
    const int sr = lane >> 2;          // row within 16-row chunk
    const int sc = (lane & 3) * 8;     // ushort col within 32

    f32x4 acc[4][4];
#pragma unroll
    for (int m = 0; m < 4; ++m)
#pragma unroll
        for (int n = 0; n < 4; ++n) acc[m][n] = (f32x4)0.f;

    const int NT = K / 32;
    auto stage = [&](int t, int buf) {
        const int k0 = t * 32;
#pragma unroll
        for (int j = 0; j < 2; ++j) {
            const int c = wave + j * 4;                 // chunk 0..7 (16 rows each)
            const unsigned short* ga = A + (row0 + c * 16 + sr) * aStride + k0 + sc;
            const unsigned short* gb = Bb + (long)(col0 + c * 16 + sr) * bStride + k0 + sc;
            __builtin_amdgcn_global_load_lds((gv_t*)ga, (sv_t*)&As[buf][c * 512], 16, 0, 0);
            __builtin_amdgcn_global_load_lds((gv_t*)gb, (sv_t*)&Bs[buf][c * 512], 16, 0, 0);
        }
    };

    stage(0, 0);
    asm volatile("s_waitcnt vmcnt(0)" ::: "memory");
    __builtin_amdgcn_s_barrier();
    int cur = 0;
    for (int t = 0; t < NT; ++t) {
        if (t + 1 < NT) stage(t + 1, cur ^ 1);
        bf16x8 af[4], bfr[4];
#pragma unroll
        for (int m = 0; m < 4; ++m)
            af[m]  = *(const bf16x8*)&As[cur][(wr * 64 + m * 16 + lr) * 32 + lq * 8];
#pragma unroll
        for (int n = 0; n < 4; ++n)
            bfr[n] = *(const bf16x8*)&Bs[cur][(wc * 64 + n * 16 + lr) * 32 + lq * 8];
#pragma unroll
        for (int m = 0; m < 4; ++m)
#pragma unroll
            for (int n = 0; n < 4; ++n)
                acc[m][n] = __builtin_amdgcn_mfma_f32_16x16x32_bf16(af[m], bfr[n], acc[m][n], 0, 0, 0);
        asm volatile("s_waitcnt vmcnt(0)" ::: "memory");
        __builtin_amdgcn_s_barrier();
        cur ^= 1;
    }

    if (MODE == 0) {
        unsigned short* C = (unsigned short*)Cout;
#pragma unroll
        for (int n = 0; n < 4; ++n) {
            const int col = col0 + wc * 64 + n * 16 + lr;
            const float bc = bias ? bias[col] : 0.f;
#pragma unroll
            for (int m = 0; m < 4; ++m) {
#pragma unroll
                for (int r = 0; r < 4; ++r) {
                    const long row = row0 + wr * 64 + m * 16 + lq * 4 + r;
                    float v = acc[m][n][r] + bc;
                    if (addend) v += bf2f(addend[row * cStride + col]);
                    v *= scale;
                    if (doRelu) v = fmaxf(v, 0.f);
                    C[row * cStride + col] = f2bf(v);
                }
            }
        }
    } else if (MODE == 1) {
        float* C = (float*)Cout;
        const int b = (int)(row0 >> 10);
        int amv[4];
#pragma unroll
        for (int n = 0; n < 4; ++n)
            amv[n] = attm[b * L_ + col0 + wc * 64 + n * 16 + lr];
#pragma unroll
        for (int m = 0; m < 4; ++m) {
#pragma unroll
            for (int r = 0; r < 4; ++r) {
                const long mg = row0 + wr * 64 + m * 16 + lq * 4 + r;
                const int ql = (int)(mg & (L_ - 1));
                const bool rowAct = (it < spw[mg]) && (srcm[mg] != 0);
                const float* qr = qrel + mg * NREL;
#pragma unroll
                for (int n = 0; n < 4; ++n) {
                    const int col = col0 + wc * 64 + n * 16 + lr;
                    int dr = col - ql; dr = dr < -R_ ? -R_ : (dr > R_ ? R_ : dr);
                    const float v = (rowAct && amv[n]) ? (acc[m][n][r] + qr[dr + R_]) : -1e18f;
                    C[(mg * NSP + it) * L_ + col] = v;
                }
            }
        }
    } else {
        float* C = (float*)Cout;
#pragma unroll
        for (int n = 0; n < 4; ++n) {
            const int col = col0 + wc * 64 + n * 16 + lr;
            if (col < Nvalid) {
#pragma unroll
                for (int m = 0; m < 4; ++m)
#pragma unroll
                    for (int r = 0; r < 4; ++r) {
                        const long row = row0 + wr * 64 + m * 16 + lq * 4 + r;
                        C[row * cStride + col] = acc[m][n][r];
                    }
            }
        }
    }
}

// ---------------------------------------------------------------------------
__global__ __launch_bounds__(256) void k_zero(float4* __restrict__ p, long n4)
{
    const long i = (long)blockIdx.x * 256 + threadIdx.x;
    if (i < n4) { float4 z; z.x = z.y = z.z = z.w = 0.f; p[i] = z; }
}

__global__ __launch_bounds__(256) void k_cvt(
    const float* __restrict__ in, unsigned short* __restrict__ out, long n4)
{
    const long i = (long)blockIdx.x * 256 + threadIdx.x;
    if (i >= n4) return;
    const float4 v = ((const float4*)in)[i];
    ushort4 o; o.x = f2bf(v.x); o.y = f2bf(v.y); o.z = f2bf(v.z); o.w = f2bf(v.w);
    ((ushort4*)out)[i] = o;
}

// fp32 [rows][cols] -> bf16 [cols][rows]
__global__ __launch_bounds__(256) void k_transpose(
    const float* __restrict__ in, unsigned short* __restrict__ out, int rows, int cols)
{
    __shared__ float t[32][33];
    const int c0 = blockIdx.x * 32, r0 = blockIdx.y * 32;
    const int tx = threadIdx.x & 31, ty = threadIdx.x >> 5;
#pragma unroll
    for (int i = 0; i < 32; i += 8)
        t[ty + i][tx] = in[(long)(r0 + ty + i) * cols + c0 + tx];
    __syncthreads();
#pragma unroll
    for (int i = 0; i < 32; i += 8)
        out[(long)(c0 + ty + i) * rows + r0 + tx] = f2bf(t[tx][ty + i]);
}

// bf16 [rows][cols] -> bf16 [cols][rows], batched over z
__global__ __launch_bounds__(256) void k_transpose_bf(
    const unsigned short* __restrict__ in, unsigned short* __restrict__ out,
    int rows, int cols)
{
    __shared__ unsigned short t[32][33];
    const long zo = (long)blockIdx.z * rows * cols;
    const int c0 = blockIdx.x * 32, r0 = blockIdx.y * 32;
    const int tx = threadIdx.x & 31, ty = threadIdx.x >> 5;
#pragma unroll
    for (int i = 0; i < 32; i += 8)
        t[ty + i][tx] = in[zo + (long)(r0 + ty + i) * cols + c0 + tx];
    __syncthreads();
#pragma unroll
    for (int i = 0; i < 32; i += 8)
        out[zo + (long)(c0 + ty + i) * rows + r0 + tx] = t[tx][ty + i];
}

// ---------------------------------------------------------------------------
__global__ __launch_bounds__(256) void k_softmax(
    float* __restrict__ base, unsigned short* __restrict__ bfout)
{
    const long m = blockIdx.x;
    float* p = base + m * (long)(NSP * L_);
    const int t = threadIdx.x;
    float4 v = *reinterpret_cast<float4*>(p + 4 * t);
    float mx = fmaxf(fmaxf(v.x, v.y), fmaxf(v.z, v.w));
#pragma unroll
    for (int o = 32; o > 0; o >>= 1) mx = fmaxf(mx, __shfl_xor(mx, o, 64));
    __shared__ float redm[4];
    __shared__ float reds[4];
    const int wave = t >> 6;
    if ((t & 63) == 0) redm[wave] = mx;
    __syncthreads();
    mx = fmaxf(fmaxf(redm[0], redm[1]), fmaxf(redm[2], redm[3]));
    v.x = expf(v.x - mx); v.y = expf(v.y - mx); v.z = expf(v.z - mx); v.w = expf(v.w - mx);
    float s = v.x + v.y + v.z + v.w;
#pragma unroll
    for (int o = 32; o > 0; o >>= 1) s += __shfl_xor(s, o, 64);
    if ((t & 63) == 0) reds[wave] = s;
    __syncthreads();
    s = reds[0] + reds[1] + reds[2] + reds[3];
    const float inv = 1.0f / s;
    v.x *= inv; v.y *= inv; v.z *= inv; v.w *= inv;
    *reinterpret_cast<float4*>(p + 4 * t) = v;
    ushort4 o; o.x = f2bf(v.x); o.y = f2bf(v.y); o.z = f2bf(v.z); o.w = f2bf(v.w);
    *(ushort4*)&bfout[m * (long)L_ + 4 * t] = o;
}

// ---------------------------------------------------------------------------
__global__ __launch_bounds__(256) void k_count(const int* __restrict__ attm, float* __restrict__ counts)
{
    const int b = blockIdx.x, t = threadIdx.x;
    int c = 0;
    for (int k = t; k < L_; k += 256) c += (attm[b * L_ + k] != 0);
#pragma unroll
    for (int o = 32; o > 0; o >>= 1) c += __shfl_xor(c, o, 64);
    __shared__ int red[4];
    if ((t & 63) == 0) red[t >> 6] = c;
    __syncthreads();
    if (t == 0) counts[b] = (float)(red[0] + red[1] + red[2] + red[3]);
}

// pooled[b][d] += sum over 128 k-rows (split-K over blockIdx.z)
__global__ __launch_bounds__(256) void k_batchsum(
    const float* __restrict__ hid, const int* __restrict__ attm, float* __restrict__ pooled)
{
    const int b = blockIdx.x;
    const int d = blockIdx.y * 256 + threadIdx.x;
    const int k0 = blockIdx.z * 128;
    const float* hb = hid + (long)b * L_ * D_;
    float acc = 0.f;
    for (int k = k0; k < k0 + 128; ++k)
        acc += attm[b * L_ + k] ? hb[(long)k * D_ + d] : 0.f;
    atomicAdd(&pooled[b * D_ + d], acc);
}

// pw2[b][n] += sum_{d in chunk} pooled[b][d] * W_sp[(768+d)][n]
__global__ __launch_bounds__(256) void k_pw2(
    const float* __restrict__ pooled, const float* __restrict__ W_sp, float* __restrict__ pw2)
{
    const int b = blockIdx.x;
    const int n = blockIdx.y * 256 + threadIdx.x;
    const int d0 = blockIdx.z * 96;
    float acc = 0.f;
    for (int d = d0; d < d0 + 96; ++d)
        acc += pooled[b * D_ + d] * W_sp[(long)(D_ + d) * D_ + n];
    atomicAdd(&pw2[b * D_ + n], acc);
}

// iter-0 pooled addend (= hidc0 @ W2), bf16
__global__ __launch_bounds__(256) void k_addend0(
    const float* __restrict__ pw2, const float* __restrict__ counts,
    const int* __restrict__ srcm, unsigned short* __restrict__ out)
{
    const long idx = (long)blockIdx.x * 256 + threadIdx.x;
    const int d = (int)(idx % D_);
    const long m = idx / D_;
    const int b = (int)(m >> 10);
    const float inv = 1.0f / fmaxf(counts[b], 1.0f);
    out[idx] = f2bf(srcm[m] ? pw2[b * D_ + d] * inv : 0.0f);
}

__global__ __launch_bounds__(256) void k_masks(const int* __restrict__ spw, float* __restrict__ outM)
{
    const long idx = (long)blockIdx.x * 256 + threadIdx.x;
    const int i = (int)(idx & 3);
    const long m = idx >> 2;
    outM[idx] = (i < spw[m]) ? 1.0f : 0.0f;
}

// ---------------------------------------------------------------------------
extern "C" void kernel_launch(void* const* d_in, const int* in_sizes, int n_in,
                              void* d_out, int out_size, void* d_ws, size_t ws_size,
                              hipStream_t stream)
{
    (void)in_sizes; (void)n_in; (void)out_size; (void)ws_size;
    const float* hid     = (const float*)d_in[0];
    const float* src_hid = (const float*)d_in[1];
    const int*   spw     = (const int*)d_in[2];
    const int*   attm    = (const int*)d_in[3];
    const int*   srcm    = (const int*)d_in[4];
    const float* Wq_st = (const float*)d_in[6];
    const float* bq_st = (const float*)d_in[7];
    const float* Wk_st = (const float*)d_in[8];
    const float* bk_st = (const float*)d_in[9];
    const float* rel_st= (const float*)d_in[10];
    const float* Wq_ed = (const float*)d_in[11];
    const float* bq_ed = (const float*)d_in[12];
    const float* Wk_ed = (const float*)d_in[13];
    const float* bk_ed = (const float*)d_in[14];
    const float* rel_ed= (const float*)d_in[15];
    const float* W_sp  = (const float*)d_in[16];
    const float* b_sp  = (const float*)d_in[17];

    float* out      = (float*)d_out;
    float* outSts   = out;
    float* outEds   = out + (long)B_ * L_ * NSP * L_;
    float* outMasks = outEds + (long)B_ * L_ * NSP * L_;

    const long S = (long)B_ * L_ * D_;
    char* wsB = (char*)d_ws;
    auto take = [&](size_t bytes) -> char* {
        char* p = wsB; wsB += (bytes + 255) & ~(size_t)255; return p;
    };
    unsigned short* hid_bf  = (unsigned short*)take(S * 2);
    unsigned short* src_bf  = (unsigned short*)take(S * 2);
    unsigned short* kst     = (unsigned short*)take(S * 2);
    unsigned short* ked     = (unsigned short*)take(S * 2);
    unsigned short* h1a     = (unsigned short*)take(S * 2);
    unsigned short* h1b     = (unsigned short*)take(S * 2);
    unsigned short* h2a     = (unsigned short*)take(S * 2);
    unsigned short* h2b     = (unsigned short*)take(S * 2);
    unsigned short* tmpQ    = (unsigned short*)take(S * 2);
    unsigned short* tmpP    = (unsigned short*)take(S * 2);   // also hidW2 staging
    unsigned short* hidW2T  = (unsigned short*)take(S * 2);   // [B][D][L]
    unsigned short* add0    = (unsigned short*)take(S * 2);
    unsigned short* WqTst   = (unsigned short*)take((long)D_ * D_ * 2);
    unsigned short* WkTst   = (unsigned short*)take((long)D_ * D_ * 2);
    unsigned short* WqTed   = (unsigned short*)take((long)D_ * D_ * 2);
    unsigned short* WkTed   = (unsigned short*)take((long)D_ * D_ * 2);
    unsigned short* W1T     = (unsigned short*)take((long)D_ * D_ * 2);
    unsigned short* W2T     = (unsigned short*)take((long)D_ * D_ * 2);
    unsigned short* relbst  = (unsigned short*)take((long)128 * D_ * 2);
    unsigned short* relbed  = (unsigned short*)take((long)128 * D_ * 2);
    unsigned short* attn_st = (unsigned short*)take((long)B_ * L_ * L_ * 2);
    unsigned short* attn_ed = (unsigned short*)take((long)B_ * L_ * L_ * 2);
    float* qrelb  = (float*)take((long)B_ * L_ * NREL * 4);
    float* pooled = (float*)take((long)B_ * D_ * 4);
    float* pw2    = (float*)take((long)B_ * D_ * 4);
    float* counts = (float*)take(256);

    const float invs = 1.0f / sqrtf((float)D_);
    const dim3 gP(D_ / 128, (B_ * L_) / 128);   // (6, 64)
    const dim3 gS(L_ / 128, (B_ * L_) / 128);   // (8, 64)
    const dim3 gQ(1, (B_ * L_) / 128);          // (1, 64)
    const long BB = (long)L_ * D_;              // 786432
    const int  NOB = 1 << 30;

    // ---- one-time prep
    k_zero<<<(128 * D_ * 2 * 2 / 16 + 255) / 256, 256, 0, stream>>>((float4*)relbst, 128L * D_ * 2 * 2 / 16);
    k_zero<<<(B_ * D_ * 2 * 4 / 16 + 255) / 256, 256, 0, stream>>>((float4*)pooled, (long)B_ * D_ * 2 * 4 / 16);
    k_cvt<<<(int)(S / 4 / 256), 256, 0, stream>>>(hid, hid_bf, S / 4);
    k_cvt<<<(int)(S / 4 / 256), 256, 0, stream>>>(src_hid, src_bf, S / 4);
    k_cvt<<<(NREL * D_ / 4 + 255) / 256, 256, 0, stream>>>(rel_st, relbst, NREL * D_ / 4);
    k_cvt<<<(NREL * D_ / 4 + 255) / 256, 256, 0, stream>>>(rel_ed, relbed, NREL * D_ / 4);
    k_transpose<<<dim3(D_ / 32, D_ / 32), 256, 0, stream>>>(Wq_st, WqTst, D_, D_);
    k_transpose<<<dim3(D_ / 32, D_ / 32), 256, 0, stream>>>(Wk_st, WkTst, D_, D_);
    k_transpose<<<dim3(D_ / 32, D_ / 32), 256, 0, stream>>>(Wq_ed, WqTed, D_, D_);
    k_transpose<<<dim3(D_ / 32, D_ / 32), 256, 0, stream>>>(Wk_ed, WkTed, D_, D_);
    k_transpose<<<dim3(D_ / 32, D_ / 32), 256, 0, stream>>>(W_sp, W1T, D_, D_);
    k_transpose<<<dim3(D_ / 32, D_ / 32), 256, 0, stream>>>(W_sp + (long)D_ * D_, W2T, D_, D_);
    k_count<<<B_, 256, 0, stream>>>(attm, counts);
    k_batchsum<<<dim3(B_, D_ / 256, 8), 256, 0, stream>>>(hid, attm, pooled);
    k_pw2<<<dim3(B_, D_ / 256, 8), 256, 0, stream>>>(pooled, W_sp, pw2);
    k_addend0<<<(int)(S / 256), 256, 0, stream>>>(pw2, counts, srcm, add0);
    k_masks<<<(B_ * L_ * NSP) / 256, 256, 0, stream>>>(spw, outMasks);

    // loop-invariant key projections + hid@W2 (then transpose per batch)
    k_mfma<0><<<gP, 256, 0, stream>>>(hid_bf, D_, WkTst, D_, 0, NOB, bk_st, nullptr, 1.f, 0,
                                      kst, D_, D_, nullptr, nullptr, nullptr, nullptr, 0, D_);
    k_mfma<0><<<gP, 256, 0, stream>>>(hid_bf, D_, WkTed, D_, 0, NOB, bk_ed, nullptr, 1.f, 0,
                                      ked, D_, D_, nullptr, nullptr, nullptr, nullptr, 0, D_);
    k_mfma<0><<<gP, 256, 0, stream>>>(hid_bf, D_, W2T, D_, 0, NOB, nullptr, nullptr, 1.f, 0,
                                      tmpP, D_, D_, nullptr, nullptr, nullptr, nullptr, 0, D_);
    k_transpose_bf<<<dim3(D_ / 32, L_ / 32, B_), 256, 0, stream>>>(tmpP, hidW2T, L_, D_);

    unsigned short* h1cur = nullptr; unsigned short* h2cur = nullptr;
    unsigned short* h1nxt = h1a;     unsigned short* h2nxt = h2a;

    for (int it = 0; it < NSP; ++it) {
        if (it == 0) {
            k_mfma<0><<<gP, 256, 0, stream>>>(src_bf, D_, W1T, D_, 0, NOB, b_sp, add0, 1.f, 1,
                                              h1a, D_, D_, nullptr, nullptr, nullptr, nullptr, 0, D_);
            h1cur = h1a; h2cur = h1a;
            h1nxt = h1b; h2nxt = h2a;
        } else {
            k_mfma<0><<<gP, 256, 0, stream>>>(attn_st, L_, hidW2T, L_, BB, L_, nullptr, nullptr, 1.f, 0,
                                              tmpP, D_, L_, nullptr, nullptr, nullptr, nullptr, 0, D_);
            k_mfma<0><<<gP, 256, 0, stream>>>(h1cur, D_, W1T, D_, 0, NOB, b_sp, tmpP, 1.f, 1,
                                              h1nxt, D_, D_, nullptr, nullptr, nullptr, nullptr, 0, D_);
            k_mfma<0><<<gP, 256, 0, stream>>>(attn_ed, L_, hidW2T, L_, BB, L_, nullptr, nullptr, 1.f, 0,
                                              tmpP, D_, L_, nullptr, nullptr, nullptr, nullptr, 0, D_);
            k_mfma<0><<<gP, 256, 0, stream>>>(h2cur, D_, W1T, D_, 0, NOB, b_sp, tmpP, 1.f, 1,
                                              h2nxt, D_, D_, nullptr, nullptr, nullptr, nullptr, 0, D_);
            h1cur = h1nxt; h2cur = h2nxt;
            h1nxt = (h1cur == h1a) ? h1b : h1a;
            h2nxt = (h2cur == h2a) ? h2b : h2a;
        }
        // ---- ST attention
        k_mfma<0><<<gP, 256, 0, stream>>>(h1cur, D_, WqTst, D_, 0, NOB, bq_st, nullptr, invs, 0,
                                          tmpQ, D_, D_, nullptr, nullptr, nullptr, nullptr, 0, D_);
        k_mfma<2><<<gQ, 256, 0, stream>>>(tmpQ, D_, relbst, D_, 0, NOB, nullptr, nullptr, 1.f, 0,
                                          qrelb, NREL, D_, nullptr, nullptr, nullptr, nullptr, 0, NREL);
        k_mfma<1><<<gS, 256, 0, stream>>>(tmpQ, D_, kst, D_, BB, L_, nullptr, nullptr, 1.f, 0,
                                          outSts, 0, D_, qrelb, spw, srcm, attm, it, L_);
        k_softmax<<<B_ * L_, 256, 0, stream>>>(outSts + (long)it * L_, attn_st);
        // ---- ED attention
        k_mfma<0><<<gP, 256, 0, stream>>>(h2cur, D_, WqTed, D_, 0, NOB, bq_ed, nullptr, invs, 0,
                                          tmpQ, D_, D_, nullptr, nullptr, nullptr, nullptr, 0, D_);
        k_mfma<2><<<gQ, 256, 0, stream>>>(tmpQ, D_, relbed, D_, 0, NOB, nullptr, nullptr, 1.f, 0,
                                          qrelb, NREL, D_, nullptr, nullptr, nullptr, nullptr, 0, NREL);
        k_mfma<1><<<gS, 256, 0, stream>>>(tmpQ, D_, ked, D_, BB, L_, nullptr, nullptr, 1.f, 0,
                                          outEds, 0, D_, qrelb, spw, srcm, attm, it, L_);
        k_softmax<<<B_ * L_, 256, 0, stream>>>(outEds + (long)it * L_, attn_ed);
    }
}

// Round 4
// 1301.859 us; speedup vs baseline: 5.3378x; 1.0782x over previous
//
#include <hip/hip_runtime.h>
#include <math.h>

#define B_   8
#define L_   1024
#define D_   768
#define R_   16
#define NSP  4
#define NREL 33
#define NQ   896   // 768 q-cols + 128 rel-cols (33 valid)

typedef __attribute__((ext_vector_type(8))) short bf16x8;
typedef __attribute__((ext_vector_type(4))) float f32x4;
typedef __attribute__((address_space(1))) const void gv_t;
typedef __attribute__((address_space(3))) void sv_t;

__device__ __forceinline__ unsigned short f2bf(float f) {
    unsigned int u = __float_as_uint(f);
    u += 0x7fff + ((u >> 16) & 1);          // RNE
    return (unsigned short)(u >> 16);
}
__device__ __forceinline__ float bf2f(unsigned short s) {
    return __uint_as_float(((unsigned int)s) << 16);
}

struct PSet {
    const unsigned short* A;
    const unsigned short* Bn;
    const float*          bias;
    const unsigned short* addend;
    void*                 Cout;
    float*                qrel;    // MODE1: input (const use); MODE3: output
};
struct PSet3 { PSet s[3]; };

// ---------------------------------------------------------------------------
// NT bf16 MFMA GEMM, 128x128 tile, BK=32, 4 waves (2x2), 64x64/wave.
// global_load_lds width=16, linear LDS, double-buffered 2-phase schedule.
// z (blockIdx.z) selects the pointer set.
// MODE 0: bf16 out = relu?((acc + bias[col] + addend[row,col]) * scale)
// MODE 1: scores -> fp32 out[(m*NSP+it)*L + col], + qrel gather + mask
// MODE 3: fused q-proj: col<768 -> bf16 Cout; col in [768,768+33) -> f32 qrel
template<int MODE>
__global__ __launch_bounds__(256) void k_mfma(
    PSet3 ps, long aStride, long bStride, long bBatch, int batchRows,
    float scale, int doRelu, long cStride, int K,
    const int* __restrict__ spw, const int* __restrict__ srcm,
    const int* __restrict__ attm, int it)
{
    PSet p;
    if (blockIdx.z == 0)      p = ps.s[0];
    else if (blockIdx.z == 1) p = ps.s[1];
    else                      p = ps.s[2];

    __shared__ unsigned short As[2][128 * 32];
    __shared__ unsigned short Bs[2][128 * 32];
    const int tid  = threadIdx.x;
    const int lane = tid & 63;
    const int wave = tid >> 6;
    const int wr = wave >> 1, wc = wave & 1;
    const int lq = lane >> 4, lr = lane & 15;
    const long row0 = (long)blockIdx.y * 128;
    const int  col0 = blockIdx.x * 128;
    const unsigned short* Bb = p.Bn + (row0 / batchRows) * bBatch;
    const int sr = lane >> 2;
    const int sc = (lane & 3) * 8;

    f32x4 acc[4][4];
#pragma unroll
    for (int m = 0; m < 4; ++m)
#pragma unroll
        for (int n = 0; n < 4; ++n) acc[m][n] = (f32x4)0.f;

    const int NT = K / 32;
    auto stage = [&](int t, int buf) {
        const int k0 = t * 32;
#pragma unroll
        for (int j = 0; j < 2; ++j) {
            const int c = wave + j * 4;
            const unsigned short* ga = p.A + (row0 + c * 16 + sr) * aStride + k0 + sc;
            const unsigned short* gb = Bb + (long)(col0 + c * 16 + sr) * bStride + k0 + sc;
            __builtin_amdgcn_global_load_lds((gv_t*)ga, (sv_t*)&As[buf][c * 512], 16, 0, 0);
            __builtin_amdgcn_global_load_lds((gv_t*)gb, (sv_t*)&Bs[buf][c * 512], 16, 0, 0);
        }
    };

    stage(0, 0);
    asm volatile("s_waitcnt vmcnt(0)" ::: "memory");
    __builtin_amdgcn_s_barrier();
    int cur = 0;
    for (int t = 0; t < NT; ++t) {
        if (t + 1 < NT) stage(t + 1, cur ^ 1);
        bf16x8 af[4], bfr[4];
#pragma unroll
        for (int m = 0; m < 4; ++m)
            af[m]  = *(const bf16x8*)&As[cur][(wr * 64 + m * 16 + lr) * 32 + lq * 8];
#pragma unroll
        for (int n = 0; n < 4; ++n)
            bfr[n] = *(const bf16x8*)&Bs[cur][(wc * 64 + n * 16 + lr) * 32 + lq * 8];
#pragma unroll
        for (int m = 0; m < 4; ++m)
#pragma unroll
            for (int n = 0; n < 4; ++n)
                acc[m][n] = __builtin_amdgcn_mfma_f32_16x16x32_bf16(af[m], bfr[n], acc[m][n], 0, 0, 0);
        asm volatile("s_waitcnt vmcnt(0)" ::: "memory");
        __builtin_amdgcn_s_barrier();
        cur ^= 1;
    }

    if (MODE == 0) {
        unsigned short* C = (unsigned short*)p.Cout;
#pragma unroll
        for (int n = 0; n < 4; ++n) {
            const int col = col0 + wc * 64 + n * 16 + lr;
            const float bc = p.bias ? p.bias[col] : 0.f;
#pragma unroll
            for (int m = 0; m < 4; ++m) {
#pragma unroll
                for (int r = 0; r < 4; ++r) {
                    const long row = row0 + wr * 64 + m * 16 + lq * 4 + r;
                    float v = acc[m][n][r] + bc;
                    if (p.addend) v += bf2f(p.addend[row * cStride + col]);
                    v *= scale;
                    if (doRelu) v = fmaxf(v, 0.f);
                    C[row * cStride + col] = f2bf(v);
                }
            }
        }
    } else if (MODE == 1) {
        float* C = (float*)p.Cout;
        const float* qrel = p.qrel;
        const int b = (int)(row0 >> 10);
        int amv[4];
#pragma unroll
        for (int n = 0; n < 4; ++n)
            amv[n] = attm[b * L_ + col0 + wc * 64 + n * 16 + lr];
#pragma unroll
        for (int m = 0; m < 4; ++m) {
#pragma unroll
            for (int r = 0; r < 4; ++r) {
                const long mg = row0 + wr * 64 + m * 16 + lq * 4 + r;
                const int ql = (int)(mg & (L_ - 1));
                const bool rowAct = (it < spw[mg]) && (srcm[mg] != 0);
                const float* qr = qrel + mg * NREL;
#pragma unroll
                for (int n = 0; n < 4; ++n) {
                    const int col = col0 + wc * 64 + n * 16 + lr;
                    int dr = col - ql; dr = dr < -R_ ? -R_ : (dr > R_ ? R_ : dr);
                    const float v = (rowAct && amv[n]) ? (acc[m][n][r] + qr[dr + R_]) : -1e18f;
                    C[(mg * NSP + it) * L_ + col] = v;
                }
            }
        }
    } else {   // MODE 3
        unsigned short* Cq = (unsigned short*)p.Cout;
        float* qout = p.qrel;
#pragma unroll
        for (int n = 0; n < 4; ++n) {
            const int col = col0 + wc * 64 + n * 16 + lr;
            const float bc = p.bias[col];
            if (col < D_) {
#pragma unroll
                for (int m = 0; m < 4; ++m)
#pragma unroll
                    for (int r = 0; r < 4; ++r) {
                        const long row = row0 + wr * 64 + m * 16 + lq * 4 + r;
                        Cq[row * (long)D_ + col] = f2bf((acc[m][n][r] + bc) * scale);
                    }
            } else if (col - D_ < NREL) {
                const int rc = col - D_;
#pragma unroll
                for (int m = 0; m < 4; ++m)
#pragma unroll
                    for (int r = 0; r < 4; ++r) {
                        const long row = row0 + wr * 64 + m * 16 + lq * 4 + r;
                        qout[row * NREL + rc] = (acc[m][n][r] + bc) * scale;
                    }
            }
        }
    }
}

// ---------------------------------------------------------------------------
__global__ __launch_bounds__(256) void k_zero(float4* __restrict__ p, long n4)
{
    const long i = (long)blockIdx.x * 256 + threadIdx.x;
    if (i < n4) { float4 z; z.x = z.y = z.z = z.w = 0.f; p[i] = z; }
}

__global__ __launch_bounds__(256) void k_cvt(
    const float* __restrict__ in, unsigned short* __restrict__ out, long n4)
{
    const long i = (long)blockIdx.x * 256 + threadIdx.x;
    if (i >= n4) return;
    const float4 v = ((const float4*)in)[i];
    ushort4 o; o.x = f2bf(v.x); o.y = f2bf(v.y); o.z = f2bf(v.z); o.w = f2bf(v.w);
    ((ushort4*)out)[i] = o;
}

// fp32 [rows][cols] -> bf16 [cols][rows]
__global__ __launch_bounds__(256) void k_transpose(
    const float* __restrict__ in, unsigned short* __restrict__ out, int rows, int cols)
{
    __shared__ float t[32][33];
    const int c0 = blockIdx.x * 32, r0 = blockIdx.y * 32;
    const int tx = threadIdx.x & 31, ty = threadIdx.x >> 5;
#pragma unroll
    for (int i = 0; i < 32; i += 8)
        t[ty + i][tx] = in[(long)(r0 + ty + i) * cols + c0 + tx];
    __syncthreads();
#pragma unroll
    for (int i = 0; i < 32; i += 8)
        out[(long)(c0 + ty + i) * rows + r0 + tx] = f2bf(t[tx][ty + i]);
}

// bf16 [rows][cols] -> bf16 [cols][rows], batched over z
__global__ __launch_bounds__(256) void k_transpose_bf(
    const unsigned short* __restrict__ in, unsigned short* __restrict__ out,
    int rows, int cols)
{
    __shared__ unsigned short t[32][33];
    const long zo = (long)blockIdx.z * rows * cols;
    const int c0 = blockIdx.x * 32, r0 = blockIdx.y * 32;
    const int tx = threadIdx.x & 31, ty = threadIdx.x >> 5;
#pragma unroll
    for (int i = 0; i < 32; i += 8)
        t[ty + i][tx] = in[zo + (long)(r0 + ty + i) * cols + c0 + tx];
    __syncthreads();
#pragma unroll
    for (int i = 0; i < 32; i += 8)
        out[zo + (long)(c0 + ty + i) * rows + r0 + tx] = t[tx][ty + i];
}

// ---------------------------------------------------------------------------
// biasQ[896]: [0..767]=bq; [768+r]=bq.rel[r] for r<33 else 0
__global__ __launch_bounds__(128) void k_biasq(
    const float* __restrict__ bq, const float* __restrict__ rel, float* __restrict__ out)
{
    const int i = blockIdx.x * 128 + threadIdx.x;
    if (i >= NQ) return;
    if (i < D_) { out[i] = bq[i]; return; }
    const int r = i - D_;
    float a = 0.f;
    if (r < NREL)
        for (int d = 0; d < D_; ++d) a += bq[d] * rel[(long)r * D_ + d];
    out[i] = a;
}

// ---------------------------------------------------------------------------
// row softmax over L=1024 (rows strided NSP*L) + bf16 copy; z selects st/ed
__global__ __launch_bounds__(256) void k_softmax(
    float* __restrict__ base0, float* __restrict__ base1,
    unsigned short* __restrict__ bf0, unsigned short* __restrict__ bf1)
{
    float* base = blockIdx.y ? base1 : base0;
    unsigned short* bfout = blockIdx.y ? bf1 : bf0;
    const long m = blockIdx.x;
    float* p = base + m * (long)(NSP * L_);
    const int t = threadIdx.x;
    float4 v = *reinterpret_cast<float4*>(p + 4 * t);
    float mx = fmaxf(fmaxf(v.x, v.y), fmaxf(v.z, v.w));
#pragma unroll
    for (int o = 32; o > 0; o >>= 1) mx = fmaxf(mx, __shfl_xor(mx, o, 64));
    __shared__ float redm[4];
    __shared__ float reds[4];
    const int wave = t >> 6;
    if ((t & 63) == 0) redm[wave] = mx;
    __syncthreads();
    mx = fmaxf(fmaxf(redm[0], redm[1]), fmaxf(redm[2], redm[3]));
    v.x = expf(v.x - mx); v.y = expf(v.y - mx); v.z = expf(v.z - mx); v.w = expf(v.w - mx);
    float s = v.x + v.y + v.z + v.w;
#pragma unroll
    for (int o = 32; o > 0; o >>= 1) s += __shfl_xor(s, o, 64);
    if ((t & 63) == 0) reds[wave] = s;
    __syncthreads();
    s = reds[0] + reds[1] + reds[2] + reds[3];
    const float inv = 1.0f / s;
    v.x *= inv; v.y *= inv; v.z *= inv; v.w *= inv;
    *reinterpret_cast<float4*>(p + 4 * t) = v;
    ushort4 o; o.x = f2bf(v.x); o.y = f2bf(v.y); o.z = f2bf(v.z); o.w = f2bf(v.w);
    *(ushort4*)&bfout[m * (long)L_ + 4 * t] = o;
}

// ---------------------------------------------------------------------------
__global__ __launch_bounds__(256) void k_count(const int* __restrict__ attm, float* __restrict__ counts)
{
    const int b = blockIdx.x, t = threadIdx.x;
    int c = 0;
    for (int k = t; k < L_; k += 256) c += (attm[b * L_ + k] != 0);
#pragma unroll
    for (int o = 32; o > 0; o >>= 1) c += __shfl_xor(c, o, 64);
    __shared__ int red[4];
    if ((t & 63) == 0) red[t >> 6] = c;
    __syncthreads();
    if (t == 0) counts[b] = (float)(red[0] + red[1] + red[2] + red[3]);
}

__global__ __launch_bounds__(256) void k_batchsum(
    const float* __restrict__ hid, const int* __restrict__ attm, float* __restrict__ pooled)
{
    const int b = blockIdx.x;
    const int d = blockIdx.y * 256 + threadIdx.x;
    const int k0 = blockIdx.z * 128;
    const float* hb = hid + (long)b * L_ * D_;
    float acc = 0.f;
    for (int k = k0; k < k0 + 128; ++k)
        acc += attm[b * L_ + k] ? hb[(long)k * D_ + d] : 0.f;
    atomicAdd(&pooled[b * D_ + d], acc);
}

__global__ __launch_bounds__(256) void k_pw2(
    const float* __restrict__ pooled, const float* __restrict__ W_sp, float* __restrict__ pw2)
{
    const int b = blockIdx.x;
    const int n = blockIdx.y * 256 + threadIdx.x;
    const int d0 = blockIdx.z * 96;
    float acc = 0.f;
    for (int d = d0; d < d0 + 96; ++d)
        acc += pooled[b * D_ + d] * W_sp[(long)(D_ + d) * D_ + n];
    atomicAdd(&pw2[b * D_ + n], acc);
}

__global__ __launch_bounds__(256) void k_addend0(
    const float* __restrict__ pw2, const float* __restrict__ counts,
    const int* __restrict__ srcm, unsigned short* __restrict__ out)
{
    const long idx = (long)blockIdx.x * 256 + threadIdx.x;
    const int d = (int)(idx % D_);
    const long m = idx / D_;
    const int b = (int)(m >> 10);
    const float inv = 1.0f / fmaxf(counts[b], 1.0f);
    out[idx] = f2bf(srcm[m] ? pw2[b * D_ + d] * inv : 0.0f);
}

__global__ __launch_bounds__(256) void k_masks(const int* __restrict__ spw, float* __restrict__ outM)
{
    const long idx = (long)blockIdx.x * 256 + threadIdx.x;
    const int i = (int)(idx & 3);
    const long m = idx >> 2;
    outM[idx] = (i < spw[m]) ? 1.0f : 0.0f;
}

// ---------------------------------------------------------------------------
extern "C" void kernel_launch(void* const* d_in, const int* in_sizes, int n_in,
                              void* d_out, int out_size, void* d_ws, size_t ws_size,
                              hipStream_t stream)
{
    (void)in_sizes; (void)n_in; (void)out_size; (void)ws_size;
    const float* hid     = (const float*)d_in[0];
    const float* src_hid = (const float*)d_in[1];
    const int*   spw     = (const int*)d_in[2];
    const int*   attm    = (const int*)d_in[3];
    const int*   srcm    = (const int*)d_in[4];
    const float* Wq_st = (const float*)d_in[6];
    const float* bq_st = (const float*)d_in[7];
    const float* Wk_st = (const float*)d_in[8];
    const float* bk_st = (const float*)d_in[9];
    const float* rel_st= (const float*)d_in[10];
    const float* Wq_ed = (const float*)d_in[11];
    const float* bq_ed = (const float*)d_in[12];
    const float* Wk_ed = (const float*)d_in[13];
    const float* bk_ed = (const float*)d_in[14];
    const float* rel_ed= (const float*)d_in[15];
    const float* W_sp  = (const float*)d_in[16];
    const float* b_sp  = (const float*)d_in[17];

    float* out      = (float*)d_out;
    float* outSts   = out;
    float* outEds   = out + (long)B_ * L_ * NSP * L_;
    float* outMasks = outEds + (long)B_ * L_ * NSP * L_;

    const long S = (long)B_ * L_ * D_;
    char* wsB = (char*)d_ws;
    auto take = [&](size_t bytes) -> char* {
        char* p = wsB; wsB += (bytes + 255) & ~(size_t)255; return p;
    };
    unsigned short* hid_bf   = (unsigned short*)take(S * 2);
    unsigned short* src_bf   = (unsigned short*)take(S * 2);
    unsigned short* kst      = (unsigned short*)take(S * 2);
    unsigned short* ked      = (unsigned short*)take(S * 2);
    unsigned short* h1a      = (unsigned short*)take(S * 2);
    unsigned short* h1b      = (unsigned short*)take(S * 2);
    unsigned short* h2a      = (unsigned short*)take(S * 2);
    unsigned short* h2b      = (unsigned short*)take(S * 2);
    unsigned short* tmpQst   = (unsigned short*)take(S * 2);
    unsigned short* tmpQed   = (unsigned short*)take(S * 2);
    unsigned short* tmpPst   = (unsigned short*)take(S * 2);   // also hid@W2 staging
    unsigned short* tmpPed   = (unsigned short*)take(S * 2);
    unsigned short* hidW2T   = (unsigned short*)take(S * 2);   // [B][D][L]
    unsigned short* add0     = (unsigned short*)take(S * 2);
    unsigned short* WqExtSt  = (unsigned short*)take((long)NQ * D_ * 2);
    unsigned short* WqExtEd  = (unsigned short*)take((long)NQ * D_ * 2);
    unsigned short* WkTst    = (unsigned short*)take((long)D_ * D_ * 2);
    unsigned short* WkTed    = (unsigned short*)take((long)D_ * D_ * 2);
    unsigned short* W1T      = (unsigned short*)take((long)D_ * D_ * 2);
    unsigned short* W2T      = (unsigned short*)take((long)D_ * D_ * 2);
    unsigned short* WqBfSt   = (unsigned short*)take((long)D_ * D_ * 2);
    unsigned short* WqBfEd   = (unsigned short*)take((long)D_ * D_ * 2);
    unsigned short* relbst   = (unsigned short*)take((long)128 * D_ * 2);  // contiguous w/ relbed
    unsigned short* relbed   = (unsigned short*)take((long)128 * D_ * 2);
    unsigned short* attn_st  = (unsigned short*)take((long)B_ * L_ * L_ * 2);
    unsigned short* attn_ed  = (unsigned short*)take((long)B_ * L_ * L_ * 2);
    float* qrelbSt = (float*)take((long)B_ * L_ * NREL * 4);
    float* qrelbEd = (float*)take((long)B_ * L_ * NREL * 4);
    float* biasQst = (float*)take(NQ * 4);
    float* biasQed = (float*)take(NQ * 4);
    float* pooled  = (float*)take((long)B_ * D_ * 4);   // contiguous w/ pw2
    float* pw2     = (float*)take((long)B_ * D_ * 4);
    float* counts  = (float*)take(256);

    const float invs = 1.0f / sqrtf((float)D_);
    const long BB   = (long)L_ * D_;
    const int  NOB  = 1 << 30;

    PSet3 ps;
    auto set = [&](int i, const unsigned short* A, const unsigned short* Bn,
                   const float* bias, const unsigned short* addend, void* C, float* qr) {
        ps.s[i] = PSet{A, Bn, bias, addend, C, qr};
    };

    // ---- one-time prep
    k_zero<<<(int)((128L * D_ * 2 * 2 / 16 + 255) / 256), 256, 0, stream>>>((float4*)relbst, 128L * D_ * 2 * 2 / 16);
    k_zero<<<(int)(((long)B_ * D_ * 2 * 4 / 16 + 255) / 256), 256, 0, stream>>>((float4*)pooled, (long)B_ * D_ * 2 * 4 / 16);
    k_cvt<<<(int)(S / 4 / 256), 256, 0, stream>>>(hid, hid_bf, S / 4);
    k_cvt<<<(int)(S / 4 / 256), 256, 0, stream>>>(src_hid, src_bf, S / 4);
    k_cvt<<<(NREL * D_ / 4 + 255) / 256, 256, 0, stream>>>(rel_st, relbst, NREL * D_ / 4);
    k_cvt<<<(NREL * D_ / 4 + 255) / 256, 256, 0, stream>>>(rel_ed, relbed, NREL * D_ / 4);
    k_cvt<<<(int)((long)D_ * D_ / 4 / 256), 256, 0, stream>>>(Wq_st, WqBfSt, (long)D_ * D_ / 4);
    k_cvt<<<(int)((long)D_ * D_ / 4 / 256), 256, 0, stream>>>(Wq_ed, WqBfEd, (long)D_ * D_ / 4);
    k_transpose<<<dim3(D_ / 32, D_ / 32), 256, 0, stream>>>(Wq_st, WqExtSt, D_, D_);
    k_transpose<<<dim3(D_ / 32, D_ / 32), 256, 0, stream>>>(Wq_ed, WqExtEd, D_, D_);
    k_transpose<<<dim3(D_ / 32, D_ / 32), 256, 0, stream>>>(Wk_st, WkTst, D_, D_);
    k_transpose<<<dim3(D_ / 32, D_ / 32), 256, 0, stream>>>(Wk_ed, WkTed, D_, D_);
    k_transpose<<<dim3(D_ / 32, D_ / 32), 256, 0, stream>>>(W_sp, W1T, D_, D_);
    k_transpose<<<dim3(D_ / 32, D_ / 32), 256, 0, stream>>>(W_sp + (long)D_ * D_, W2T, D_, D_);
    k_biasq<<<NQ / 128, 128, 0, stream>>>(bq_st, rel_st, biasQst);
    k_biasq<<<NQ / 128, 128, 0, stream>>>(bq_ed, rel_ed, biasQed);
    k_count<<<B_, 256, 0, stream>>>(attm, counts);
    k_batchsum<<<dim3(B_, D_ / 256, 8), 256, 0, stream>>>(hid, attm, pooled);
    k_pw2<<<dim3(B_, D_ / 256, 8), 256, 0, stream>>>(pooled, W_sp, pw2);
    k_addend0<<<(int)(S / 256), 256, 0, stream>>>(pw2, counts, srcm, add0);
    k_masks<<<(B_ * L_ * NSP) / 256, 256, 0, stream>>>(spw, outMasks);

    // Wqrel bottom rows of WqExt: C[r,e] = rel[r,:] . Wq[e,:]  (M=128,N=768,K=768)
    set(0, relbst, WqBfSt, nullptr, nullptr, WqExtSt + (long)D_ * D_, nullptr);
    set(1, relbed, WqBfEd, nullptr, nullptr, WqExtEd + (long)D_ * D_, nullptr);
    k_mfma<0><<<dim3(D_ / 128, 1, 2), 256, 0, stream>>>(ps, D_, D_, 0, NOB, 1.f, 0, D_, D_,
                                                        nullptr, nullptr, nullptr, 0);

    // loop-invariant: kst, ked, hid@W2 (one z=3 dispatch)
    set(0, hid_bf, WkTst, bk_st, nullptr, kst, nullptr);
    set(1, hid_bf, WkTed, bk_ed, nullptr, ked, nullptr);
    set(2, hid_bf, W2T,   nullptr, nullptr, tmpPst, nullptr);
    k_mfma<0><<<dim3(D_ / 128, (B_ * L_) / 128, 3), 256, 0, stream>>>(ps, D_, D_, 0, NOB, 1.f, 0, D_, D_,
                                                                      nullptr, nullptr, nullptr, 0);
    k_transpose_bf<<<dim3(D_ / 32, L_ / 32, B_), 256, 0, stream>>>(tmpPst, hidW2T, L_, D_);

    unsigned short* h1cur = nullptr; unsigned short* h2cur = nullptr;
    unsigned short* h1nxt = h1a;     unsigned short* h2nxt = h2a;

    for (int it = 0; it < NSP; ++it) {
        if (it == 0) {
            set(0, src_bf, W1T, b_sp, add0, h1a, nullptr);
            k_mfma<0><<<dim3(D_ / 128, (B_ * L_) / 128, 1), 256, 0, stream>>>(
                ps, D_, D_, 0, NOB, 1.f, 1, D_, D_, nullptr, nullptr, nullptr, 0);
            h1cur = h1a; h2cur = h1a;
            h1nxt = h1b; h2nxt = h2a;
        } else {
            // pooling: tmpP = attn @ hidW2T   (K = L)
            set(0, attn_st, hidW2T, nullptr, nullptr, tmpPst, nullptr);
            set(1, attn_ed, hidW2T, nullptr, nullptr, tmpPed, nullptr);
            k_mfma<0><<<dim3(D_ / 128, (B_ * L_) / 128, 2), 256, 0, stream>>>(
                ps, L_, L_, BB, L_, 1.f, 0, D_, L_, nullptr, nullptr, nullptr, 0);
            // concat: hN = relu(hcur @ W1 + tmpP + b_sp)
            set(0, h1cur, W1T, b_sp, tmpPst, h1nxt, nullptr);
            set(1, h2cur, W1T, b_sp, tmpPed, h2nxt, nullptr);
            k_mfma<0><<<dim3(D_ / 128, (B_ * L_) / 128, 2), 256, 0, stream>>>(
                ps, D_, D_, 0, NOB, 1.f, 1, D_, D_, nullptr, nullptr, nullptr, 0);
            h1cur = h1nxt; h2cur = h2nxt;
            h1nxt = (h1cur == h1a) ? h1b : h1a;
            h2nxt = (h2cur == h2a) ? h2b : h2a;
        }
        // fused q-proj + qrel (N=896)
        set(0, h1cur, WqExtSt, biasQst, nullptr, tmpQst, qrelbSt);
        set(1, h2cur, WqExtEd, biasQed, nullptr, tmpQed, qrelbEd);
        k_mfma<3><<<dim3(NQ / 128, (B_ * L_) / 128, 2), 256, 0, stream>>>(
            ps, D_, D_, 0, NOB, invs, 0, D_, D_, nullptr, nullptr, nullptr, 0);
        // scores (K = D)
        set(0, tmpQst, kst, nullptr, nullptr, outSts, qrelbSt);
        set(1, tmpQed, ked, nullptr, nullptr, outEds, qrelbEd);
        k_mfma<1><<<dim3(L_ / 128, (B_ * L_) / 128, 2), 256, 0, stream>>>(
            ps, D_, D_, BB, L_, 1.f, 0, 0, D_, spw, srcm, attm, it);
        // softmax st+ed
        k_softmax<<<dim3(B_ * L_, 2), 256, 0, stream>>>(
            outSts + (long)it * L_, outEds + (long)it * L_, attn_st, attn_ed);
    }
}

// Round 5
// 1110.442 us; speedup vs baseline: 6.2579x; 1.1724x over previous
//
#include <hip/hip_runtime.h>
#include <math.h>

#define B_   8
#define L_   1024
#define D_   768
#define R_   16
#define NSP  4
#define NREL 33
#define NQ   896   // 768 qw-cols + 128 rel-cols (33 valid)

typedef __attribute__((ext_vector_type(8))) short bf16x8;
typedef __attribute__((ext_vector_type(4))) float f32x4;
typedef __attribute__((address_space(1))) const void gv_t;
typedef __attribute__((address_space(3))) void sv_t;

__device__ __forceinline__ unsigned short f2bf(float f) {
    unsigned int u = __float_as_uint(f);
    u += 0x7fff + ((u >> 16) & 1);          // RNE
    return (unsigned short)(u >> 16);
}
__device__ __forceinline__ float bf2f(unsigned short s) {
    return __uint_as_float(((unsigned int)s) << 16);
}

struct PSet {
    const unsigned short* A0;
    const unsigned short* B0;
    const unsigned short* A1;   // dual-K phase 2 (nullptr if unused)
    const unsigned short* B1;
    const float*          bias;
    const unsigned short* addend;
    void*                 Cout;
    float*                qrel;   // MODE1: input; MODE3: output
    long                  mValid; // blocks with row0 >= mValid exit
    int                   relu;
};
struct PSet4 { PSet s[4]; };

// ---------------------------------------------------------------------------
// NT bf16 MFMA GEMM, 128x128 tile, BK=32, 4 waves (2x2), 64x64/wave.
// global_load_lds width=16, linear LDS, double-buffered 2-phase schedule.
// Dual-K: K-space = K0 (A0,B0) ++ K1 (A1,B1), same accumulator.
// blockIdx.z selects pointer set.
// MODE 0: bf16 out = relu?((acc + bias[col] + addend[row,col]) * scale)
// MODE 1: scores -> fp32 out[(m*NSP+it)*L + col], + qrel gather + mask
// MODE 3: fused qw-proj: col<768 -> bf16 Cout; col in [768,801) -> f32 qrel
template<int MODE>
__global__ __launch_bounds__(256) void k_mfma(
    PSet4 ps,
    long aS0, long bS0, long bB0, int bR0, int K0,
    long aS1, long bS1, long bB1, int bR1, int K1,
    float scale, long cStride,
    const int* __restrict__ spw, const int* __restrict__ srcm,
    const int* __restrict__ attm, int it)
{
    PSet p = ps.s[blockIdx.z];
    const long row0 = (long)blockIdx.y * 128;
    if (row0 >= p.mValid) return;
    const int  col0 = blockIdx.x * 128;

    __shared__ unsigned short As[2][128 * 32];
    __shared__ unsigned short Bs[2][128 * 32];
    const int tid  = threadIdx.x;
    const int lane = tid & 63;
    const int wave = tid >> 6;
    const int wr = wave >> 1, wc = wave & 1;
    const int lq = lane >> 4, lr = lane & 15;
    const unsigned short* Bb0 = p.B0 + (row0 / bR0) * bB0;
    const unsigned short* Bb1 = p.B1 ? p.B1 + (row0 / bR1) * bB1 : nullptr;
    const int sr = lane >> 2;
    const int sc = (lane & 3) * 8;

    f32x4 acc[4][4];
#pragma unroll
    for (int m = 0; m < 4; ++m)
#pragma unroll
        for (int n = 0; n < 4; ++n) acc[m][n] = (f32x4)0.f;

    const int NT0 = K0 / 32;
    const int NT  = NT0 + K1 / 32;
    auto stage = [&](int t, int buf) {
        const unsigned short* Ap; long aS; const unsigned short* Bp; long bS; int kk;
        if (t < NT0) { Ap = p.A0; aS = aS0; Bp = Bb0; bS = bS0; kk = t * 32; }
        else         { Ap = p.A1; aS = aS1; Bp = Bb1; bS = bS1; kk = (t - NT0) * 32; }
#pragma unroll
        for (int j = 0; j < 2; ++j) {
            const int c = wave + j * 4;
            const unsigned short* ga = Ap + (row0 + c * 16 + sr) * aS + kk + sc;
            const unsigned short* gb = Bp + (long)(col0 + c * 16 + sr) * bS + kk + sc;
            __builtin_amdgcn_global_load_lds((gv_t*)ga, (sv_t*)&As[buf][c * 512], 16, 0, 0);
            __builtin_amdgcn_global_load_lds((gv_t*)gb, (sv_t*)&Bs[buf][c * 512], 16, 0, 0);
        }
    };

    stage(0, 0);
    asm volatile("s_waitcnt vmcnt(0)" ::: "memory");
    __builtin_amdgcn_s_barrier();
    int cur = 0;
    for (int t = 0; t < NT; ++t) {
        if (t + 1 < NT) stage(t + 1, cur ^ 1);
        bf16x8 af[4], bfr[4];
#pragma unroll
        for (int m = 0; m < 4; ++m)
            af[m]  = *(const bf16x8*)&As[cur][(wr * 64 + m * 16 + lr) * 32 + lq * 8];
#pragma unroll
        for (int n = 0; n < 4; ++n)
            bfr[n] = *(const bf16x8*)&Bs[cur][(wc * 64 + n * 16 + lr) * 32 + lq * 8];
#pragma unroll
        for (int m = 0; m < 4; ++m)
#pragma unroll
            for (int n = 0; n < 4; ++n)
                acc[m][n] = __builtin_amdgcn_mfma_f32_16x16x32_bf16(af[m], bfr[n], acc[m][n], 0, 0, 0);
        asm volatile("s_waitcnt vmcnt(0)" ::: "memory");
        __builtin_amdgcn_s_barrier();
        cur ^= 1;
    }

    if (MODE == 0) {
        unsigned short* C = (unsigned short*)p.Cout;
#pragma unroll
        for (int n = 0; n < 4; ++n) {
            const int col = col0 + wc * 64 + n * 16 + lr;
            const float bc = p.bias ? p.bias[col] : 0.f;
#pragma unroll
            for (int m = 0; m < 4; ++m) {
#pragma unroll
                for (int r = 0; r < 4; ++r) {
                    const long row = row0 + wr * 64 + m * 16 + lq * 4 + r;
                    float v = acc[m][n][r] + bc;
                    if (p.addend) v += bf2f(p.addend[row * cStride + col]);
                    v *= scale;
                    if (p.relu) v = fmaxf(v, 0.f);
                    C[row * cStride + col] = f2bf(v);
                }
            }
        }
    } else if (MODE == 1) {
        float* C = (float*)p.Cout;
        const float* qrel = p.qrel;
        const int b = (int)(row0 >> 10);
        int amv[4];
#pragma unroll
        for (int n = 0; n < 4; ++n)
            amv[n] = attm[b * L_ + col0 + wc * 64 + n * 16 + lr];
#pragma unroll
        for (int m = 0; m < 4; ++m) {
#pragma unroll
            for (int r = 0; r < 4; ++r) {
                const long mg = row0 + wr * 64 + m * 16 + lq * 4 + r;
                const int ql = (int)(mg & (L_ - 1));
                const bool rowAct = (it < spw[mg]) && (srcm[mg] != 0);
                const float* qr = qrel + mg * NREL;
#pragma unroll
                for (int n = 0; n < 4; ++n) {
                    const int col = col0 + wc * 64 + n * 16 + lr;
                    int dr = col - ql; dr = dr < -R_ ? -R_ : (dr > R_ ? R_ : dr);
                    const float v = (rowAct && amv[n]) ? (acc[m][n][r] + qr[dr + R_]) : -1e18f;
                    C[(mg * NSP + it) * L_ + col] = v;
                }
            }
        }
    } else {   // MODE 3
        unsigned short* Cq = (unsigned short*)p.Cout;
        float* qout = p.qrel;
#pragma unroll
        for (int n = 0; n < 4; ++n) {
            const int col = col0 + wc * 64 + n * 16 + lr;
            const float bc = p.bias[col];
            if (col < D_) {
#pragma unroll
                for (int m = 0; m < 4; ++m)
#pragma unroll
                    for (int r = 0; r < 4; ++r) {
                        const long row = row0 + wr * 64 + m * 16 + lq * 4 + r;
                        Cq[row * (long)D_ + col] = f2bf((acc[m][n][r] + bc) * scale);
                    }
            } else if (col - D_ < NREL) {
                const int rc = col - D_;
#pragma unroll
                for (int m = 0; m < 4; ++m)
#pragma unroll
                    for (int r = 0; r < 4; ++r) {
                        const long row = row0 + wr * 64 + m * 16 + lq * 4 + r;
                        qout[row * NREL + rc] = (acc[m][n][r] + bc) * scale;
                    }
            }
        }
    }
}

// ---------------------------------------------------------------------------
struct Zero4 { float4* p[4]; long n4[4]; };
__global__ __launch_bounds__(256) void k_zero4(Zero4 z)
{
    long g = (long)blockIdx.x * 256 + threadIdx.x;
#pragma unroll
    for (int s = 0; s < 4; ++s) {
        if (g < z.n4[s]) {
            float4 v; v.x = v.y = v.z = v.w = 0.f;
            z.p[s][g] = v;
            return;
        }
        g -= z.n4[s];
    }
}

struct Cvt8 { const float* src[8]; unsigned short* dst[8]; long n4[8]; };
__global__ __launch_bounds__(256) void k_cvt8(Cvt8 c)
{
    long g = (long)blockIdx.x * 256 + threadIdx.x;
#pragma unroll
    for (int s = 0; s < 8; ++s) {
        if (g < c.n4[s]) {
            const float4 v = ((const float4*)c.src[s])[g];
            ushort4 o; o.x = f2bf(v.x); o.y = f2bf(v.y); o.z = f2bf(v.z); o.w = f2bf(v.w);
            ((ushort4*)c.dst[s])[g] = o;
            return;
        }
        g -= c.n4[s];
    }
}

// fp32 [rows][cols] -> bf16 [cols][rows]; z-slice offsets by rows*cols
__global__ __launch_bounds__(256) void k_transpose(
    const float* __restrict__ in, unsigned short* __restrict__ out, int rows, int cols)
{
    __shared__ float t[32][33];
    const long zo = (long)blockIdx.z * rows * cols;
    const int c0 = blockIdx.x * 32, r0 = blockIdx.y * 32;
    const int tx = threadIdx.x & 31, ty = threadIdx.x >> 5;
#pragma unroll
    for (int i = 0; i < 32; i += 8)
        t[ty + i][tx] = in[zo + (long)(r0 + ty + i) * cols + c0 + tx];
    __syncthreads();
#pragma unroll
    for (int i = 0; i < 32; i += 8)
        out[zo + (long)(c0 + ty + i) * rows + r0 + tx] = f2bf(t[tx][ty + i]);
}

// bf16 [rows][cols] -> bf16 [cols][rows], batched over z
__global__ __launch_bounds__(256) void k_transpose_bf(
    const unsigned short* __restrict__ in, unsigned short* __restrict__ out,
    int rows, int cols)
{
    __shared__ unsigned short t[32][33];
    const long zo = (long)blockIdx.z * rows * cols;
    const int c0 = blockIdx.x * 32, r0 = blockIdx.y * 32;
    const int tx = threadIdx.x & 31, ty = threadIdx.x >> 5;
#pragma unroll
    for (int i = 0; i < 32; i += 8)
        t[ty + i][tx] = in[zo + (long)(r0 + ty + i) * cols + c0 + tx];
    __syncthreads();
#pragma unroll
    for (int i = 0; i < 32; i += 8)
        out[zo + (long)(c0 + ty + i) * rows + r0 + tx] = t[tx][ty + i];
}

// ---------------------------------------------------------------------------
// biasQ[896]: [0..767] = bq@Wk^T (= sum_e bq[e]*Wk[d][e]); [768+r] = bq.rel[r]
__global__ __launch_bounds__(128) void k_biasq(
    const float* __restrict__ bq0, const float* __restrict__ bq1,
    const float* __restrict__ wk0, const float* __restrict__ wk1,
    const float* __restrict__ rel0, const float* __restrict__ rel1,
    float* __restrict__ out0, float* __restrict__ out1)
{
    const int z = blockIdx.y;
    const float* bq  = z ? bq1  : bq0;
    const float* wk  = z ? wk1  : wk0;
    const float* rel = z ? rel1 : rel0;
    float* out       = z ? out1 : out0;
    const int i = blockIdx.x * 128 + threadIdx.x;
    if (i >= NQ) return;
    float a = 0.f;
    if (i < D_) {
        const float* w = wk + (long)i * D_;
        for (int e = 0; e < D_; ++e) a += bq[e] * w[e];
    } else if (i - D_ < NREL) {
        const float* w = rel + (long)(i - D_) * D_;
        for (int e = 0; e < D_; ++e) a += bq[e] * w[e];
    }
    out[i] = a;
}

// ---------------------------------------------------------------------------
// row softmax over L=1024 (rows strided NSP*L) + bf16 copy; y selects st/ed
__global__ __launch_bounds__(256) void k_softmax(
    float* __restrict__ base0, float* __restrict__ base1,
    unsigned short* __restrict__ bf0, unsigned short* __restrict__ bf1)
{
    float* base = blockIdx.y ? base1 : base0;
    unsigned short* bfout = blockIdx.y ? bf1 : bf0;
    const long m = blockIdx.x;
    float* p = base + m * (long)(NSP * L_);
    const int t = threadIdx.x;
    float4 v = *reinterpret_cast<float4*>(p + 4 * t);
    float mx = fmaxf(fmaxf(v.x, v.y), fmaxf(v.z, v.w));
#pragma unroll
    for (int o = 32; o > 0; o >>= 1) mx = fmaxf(mx, __shfl_xor(mx, o, 64));
    __shared__ float redm[4];
    __shared__ float reds[4];
    const int wave = t >> 6;
    if ((t & 63) == 0) redm[wave] = mx;
    __syncthreads();
    mx = fmaxf(fmaxf(redm[0], redm[1]), fmaxf(redm[2], redm[3]));
    v.x = expf(v.x - mx); v.y = expf(v.y - mx); v.z = expf(v.z - mx); v.w = expf(v.w - mx);
    float s = v.x + v.y + v.z + v.w;
#pragma unroll
    for (int o = 32; o > 0; o >>= 1) s += __shfl_xor(s, o, 64);
    if ((t & 63) == 0) reds[wave] = s;
    __syncthreads();
    s = reds[0] + reds[1] + reds[2] + reds[3];
    const float inv = 1.0f / s;
    v.x *= inv; v.y *= inv; v.z *= inv; v.w *= inv;
    *reinterpret_cast<float4*>(p + 4 * t) = v;
    ushort4 o; o.x = f2bf(v.x); o.y = f2bf(v.y); o.z = f2bf(v.z); o.w = f2bf(v.w);
    *(ushort4*)&bfout[m * (long)L_ + 4 * t] = o;
}

// ---------------------------------------------------------------------------
__global__ __launch_bounds__(256) void k_count(const int* __restrict__ attm, float* __restrict__ counts)
{
    const int b = blockIdx.x, t = threadIdx.x;
    int c = 0;
    for (int k = t; k < L_; k += 256) c += (attm[b * L_ + k] != 0);
#pragma unroll
    for (int o = 32; o > 0; o >>= 1) c += __shfl_xor(c, o, 64);
    __shared__ int red[4];
    if ((t & 63) == 0) red[t >> 6] = c;
    __syncthreads();
    if (t == 0) counts[b] = (float)(red[0] + red[1] + red[2] + red[3]);
}

__global__ __launch_bounds__(256) void k_batchsum(
    const float* __restrict__ hid, const int* __restrict__ attm, float* __restrict__ pooled)
{
    const int b = blockIdx.x;
    const int d = blockIdx.y * 256 + threadIdx.x;
    const int k0 = blockIdx.z * 128;
    const float* hb = hid + (long)b * L_ * D_;
    float acc = 0.f;
    for (int k = k0; k < k0 + 128; ++k)
        acc += attm[b * L_ + k] ? hb[(long)k * D_ + d] : 0.f;
    atomicAdd(&pooled[b * D_ + d], acc);
}

__global__ __launch_bounds__(256) void k_pw2(
    const float* __restrict__ pooled, const float* __restrict__ W_sp, float* __restrict__ pw2)
{
    const int b = blockIdx.x;
    const int n = blockIdx.y * 256 + threadIdx.x;
    const int d0 = blockIdx.z * 96;
    float acc = 0.f;
    for (int d = d0; d < d0 + 96; ++d)
        acc += pooled[b * D_ + d] * W_sp[(long)(D_ + d) * D_ + n];
    atomicAdd(&pw2[b * D_ + n], acc);
}

// add0 (it-0 pooled@W2 addend, bf16) + masks output
__global__ __launch_bounds__(256) void k_addend0m(
    const float* __restrict__ pw2, const float* __restrict__ counts,
    const int* __restrict__ srcm, const int* __restrict__ spw,
    unsigned short* __restrict__ out, float* __restrict__ outM)
{
    const long idx = (long)blockIdx.x * 256 + threadIdx.x;
    const int d = (int)(idx % D_);
    const long m = idx / D_;
    const int b = (int)(m >> 10);
    const float inv = 1.0f / fmaxf(counts[b], 1.0f);
    out[idx] = f2bf(srcm[m] ? pw2[b * D_ + d] * inv : 0.0f);
    if (idx < (long)B_ * L_ * NSP)
        outM[idx] = ((int)(idx & 3) < spw[idx >> 2]) ? 1.0f : 0.0f;
}

// ---------------------------------------------------------------------------
extern "C" void kernel_launch(void* const* d_in, const int* in_sizes, int n_in,
                              void* d_out, int out_size, void* d_ws, size_t ws_size,
                              hipStream_t stream)
{
    (void)in_sizes; (void)n_in; (void)out_size; (void)ws_size;
    const float* hid     = (const float*)d_in[0];
    const float* src_hid = (const float*)d_in[1];
    const int*   spw     = (const int*)d_in[2];
    const int*   attm    = (const int*)d_in[3];
    const int*   srcm    = (const int*)d_in[4];
    const float* Wq_st = (const float*)d_in[6];
    const float* bq_st = (const float*)d_in[7];
    const float* Wk_st = (const float*)d_in[8];
    const float* bk_st = (const float*)d_in[9];   (void)bk_st;  // cancels in softmax
    const float* rel_st= (const float*)d_in[10];
    const float* Wq_ed = (const float*)d_in[11];
    const float* bq_ed = (const float*)d_in[12];
    const float* Wk_ed = (const float*)d_in[13];
    const float* bk_ed = (const float*)d_in[14];  (void)bk_ed;
    const float* rel_ed= (const float*)d_in[15];
    const float* W_sp  = (const float*)d_in[16];
    const float* b_sp  = (const float*)d_in[17];

    float* out      = (float*)d_out;
    float* outSts   = out;
    float* outEds   = out + (long)B_ * L_ * NSP * L_;
    float* outMasks = outEds + (long)B_ * L_ * NSP * L_;

    const long S = (long)B_ * L_ * D_;
    const long DD = (long)D_ * D_;
    char* wsB = (char*)d_ws;
    auto take = [&](size_t bytes) -> char* {
        char* p = wsB; wsB += (bytes + 255) & ~(size_t)255; return p;
    };
    unsigned short* hid_bf   = (unsigned short*)take(S * 2);
    unsigned short* src_bf   = (unsigned short*)take(S * 2);
    unsigned short* h1a      = (unsigned short*)take(S * 2);
    unsigned short* h1b      = (unsigned short*)take(S * 2);
    unsigned short* h2a      = (unsigned short*)take(S * 2);
    unsigned short* h2b      = (unsigned short*)take(S * 2);
    unsigned short* tmpQst   = (unsigned short*)take(S * 2);
    unsigned short* tmpQed   = (unsigned short*)take(S * 2);
    unsigned short* tmpP     = (unsigned short*)take(S * 2);   // hid@W2 staging
    unsigned short* hidW2T   = (unsigned short*)take(S * 2);   // [B][D][L]
    unsigned short* add0     = (unsigned short*)take(S * 2);
    unsigned short* WqExtSt  = (unsigned short*)take((long)NQ * D_ * 2);
    unsigned short* WqExtEd  = (unsigned short*)take((long)NQ * D_ * 2);
    unsigned short* W1T      = (unsigned short*)take(DD * 2);  // contiguous with W2T
    unsigned short* W2T      = (unsigned short*)take(DD * 2);
    unsigned short* WqBfSt   = (unsigned short*)take(DD * 2);
    unsigned short* WqBfEd   = (unsigned short*)take(DD * 2);
    unsigned short* WkBfSt   = (unsigned short*)take(DD * 2);
    unsigned short* WkBfEd   = (unsigned short*)take(DD * 2);
    unsigned short* relbst   = (unsigned short*)take((long)128 * D_ * 2);
    unsigned short* relbed   = (unsigned short*)take((long)128 * D_ * 2);
    unsigned short* attn_st  = (unsigned short*)take((long)B_ * L_ * L_ * 2);
    unsigned short* attn_ed  = (unsigned short*)take((long)B_ * L_ * L_ * 2);
    float* qrelbSt = (float*)take((long)B_ * L_ * NREL * 4);
    float* qrelbEd = (float*)take((long)B_ * L_ * NREL * 4);
    float* biasQst = (float*)take(NQ * 4);
    float* biasQed = (float*)take(NQ * 4);
    float* pooled  = (float*)take((long)B_ * D_ * 4);
    float* pw2     = (float*)take((long)B_ * D_ * 4);
    float* counts  = (float*)take(256);

    const float invs = 1.0f / sqrtf((float)D_);
    const long BB   = (long)L_ * D_;
    const int  NOB  = 1 << 30;
    const long MFULL = 1L << 40;

    PSet4 ps;
    auto set = [&](int i, const unsigned short* A0, const unsigned short* B0,
                   const unsigned short* A1, const unsigned short* B1,
                   const float* bias, const unsigned short* addend,
                   void* C, float* qr, long mValid, int relu) {
        ps.s[i] = PSet{A0, B0, A1, B1, bias, addend, C, qr, mValid, relu};
    };

    // ---- prep (consolidated) ----
    {
        Zero4 z;
        z.p[0] = (float4*)(relbst + (long)NREL * D_); z.n4[0] = (long)(128 - NREL) * D_ * 2 / 16;
        z.p[1] = (float4*)(relbed + (long)NREL * D_); z.n4[1] = (long)(128 - NREL) * D_ * 2 / 16;
        z.p[2] = (float4*)pooled;                     z.n4[2] = (long)B_ * D_ / 4;
        z.p[3] = (float4*)pw2;                        z.n4[3] = (long)B_ * D_ / 4;
        const long tot = z.n4[0] + z.n4[1] + z.n4[2] + z.n4[3];
        k_zero4<<<(int)((tot + 255) / 256), 256, 0, stream>>>(z);
    }
    {
        Cvt8 c;
        c.src[0] = hid;     c.dst[0] = hid_bf;  c.n4[0] = S / 4;
        c.src[1] = src_hid; c.dst[1] = src_bf;  c.n4[1] = S / 4;
        c.src[2] = Wq_st;   c.dst[2] = WqBfSt;  c.n4[2] = DD / 4;
        c.src[3] = Wq_ed;   c.dst[3] = WqBfEd;  c.n4[3] = DD / 4;
        c.src[4] = Wk_st;   c.dst[4] = WkBfSt;  c.n4[4] = DD / 4;
        c.src[5] = Wk_ed;   c.dst[5] = WkBfEd;  c.n4[5] = DD / 4;
        c.src[6] = rel_st;  c.dst[6] = relbst;  c.n4[6] = (long)NREL * D_ / 4;
        c.src[7] = rel_ed;  c.dst[7] = relbed;  c.n4[7] = (long)NREL * D_ / 4;
        long tot = 0; for (int i = 0; i < 8; ++i) tot += c.n4[i];
        k_cvt8<<<(int)((tot + 255) / 256), 256, 0, stream>>>(c);
    }
    k_transpose<<<dim3(D_ / 32, D_ / 32, 2), 256, 0, stream>>>(W_sp, W1T, D_, D_); // W1T, W2T
    k_biasq<<<dim3(NQ / 128, 2), 128, 0, stream>>>(bq_st, bq_ed, Wk_st, Wk_ed,
                                                   rel_st, rel_ed, biasQst, biasQed);
    k_count<<<B_, 256, 0, stream>>>(attm, counts);
    k_batchsum<<<dim3(B_, D_ / 256, 8), 256, 0, stream>>>(hid, attm, pooled);
    k_pw2<<<dim3(B_, D_ / 256, 8), 256, 0, stream>>>(pooled, W_sp, pw2);
    k_addend0m<<<(int)(S / 256), 256, 0, stream>>>(pw2, counts, srcm, spw, add0, outMasks);

    // ---- Gt (= Wk.Wq^T rows) + Wqrel (= rel.Wq^T rows) in one z=4 dispatch ----
    set(0, WkBfSt, WqBfSt, nullptr, nullptr, nullptr, nullptr, WqExtSt, nullptr, D_, 0);
    set(1, WkBfEd, WqBfEd, nullptr, nullptr, nullptr, nullptr, WqExtEd, nullptr, D_, 0);
    set(2, relbst, WqBfSt, nullptr, nullptr, nullptr, nullptr, WqExtSt + DD, nullptr, 128, 0);
    set(3, relbed, WqBfEd, nullptr, nullptr, nullptr, nullptr, WqExtEd + DD, nullptr, 128, 0);
    k_mfma<0><<<dim3(D_ / 128, D_ / 128, 4), 256, 0, stream>>>(
        ps, D_, D_, 0, NOB, D_, 0, 0, 0, NOB, 0, 1.f, D_, nullptr, nullptr, nullptr, 0);

    // ---- it-0 concat (src_bf@W1 + add0) + hid@W2, one z=2 dispatch ----
    set(0, src_bf, W1T, nullptr, nullptr, b_sp, add0, h1a, nullptr, MFULL, 1);
    set(1, hid_bf, W2T, nullptr, nullptr, nullptr, nullptr, tmpP, nullptr, MFULL, 0);
    k_mfma<0><<<dim3(D_ / 128, (B_ * L_) / 128, 2), 256, 0, stream>>>(
        ps, D_, D_, 0, NOB, D_, 0, 0, 0, NOB, 0, 1.f, D_, nullptr, nullptr, nullptr, 0);
    k_transpose_bf<<<dim3(D_ / 32, L_ / 32, B_), 256, 0, stream>>>(tmpP, hidW2T, L_, D_);

    unsigned short* h1cur = h1a; unsigned short* h2cur = h1a;
    unsigned short* h1nxt = h1b; unsigned short* h2nxt = h2a;

    for (int it = 0; it < NSP; ++it) {
        if (it > 0) {
            // fused pooling+concat: acc = attn@hidW2T (K=1024) + hcur@W1 (K=768)
            set(0, attn_st, hidW2T, h1cur, W1T, b_sp, nullptr, h1nxt, nullptr, MFULL, 1);
            set(1, attn_ed, hidW2T, h2cur, W1T, b_sp, nullptr, h2nxt, nullptr, MFULL, 1);
            k_mfma<0><<<dim3(D_ / 128, (B_ * L_) / 128, 2), 256, 0, stream>>>(
                ps, L_, L_, BB, L_, L_, D_, D_, 0, NOB, D_, 1.f, D_,
                nullptr, nullptr, nullptr, 0);
            h1cur = h1nxt; h2cur = h2nxt;
            h1nxt = (h1cur == h1a) ? h1b : h1a;
            h2nxt = (h2cur == h2a) ? h2b : h2a;
        }
        // fused qw-proj + qrel (N=896)
        set(0, h1cur, WqExtSt, nullptr, nullptr, biasQst, nullptr, tmpQst, qrelbSt, MFULL, 0);
        set(1, h2cur, WqExtEd, nullptr, nullptr, biasQed, nullptr, tmpQed, qrelbEd, MFULL, 0);
        k_mfma<3><<<dim3(NQ / 128, (B_ * L_) / 128, 2), 256, 0, stream>>>(
            ps, D_, D_, 0, NOB, D_, 0, 0, 0, NOB, 0, invs, D_, nullptr, nullptr, nullptr, 0);
        // scores: qw @ hid^T (B operand = hid_bf, shared st/ed)
        set(0, tmpQst, hid_bf, nullptr, nullptr, nullptr, nullptr, outSts, qrelbSt, MFULL, 0);
        set(1, tmpQed, hid_bf, nullptr, nullptr, nullptr, nullptr, outEds, qrelbEd, MFULL, 0);
        k_mfma<1><<<dim3(L_ / 128, (B_ * L_) / 128, 2), 256, 0, stream>>>(
            ps, D_, D_, BB, L_, D_, 0, 0, 0, NOB, 0, 1.f, 0, spw, srcm, attm, it);
        // softmax st+ed
        k_softmax<<<dim3(B_ * L_, 2), 256, 0, stream>>>(
            outSts + (long)it * L_, outEds + (long)it * L_, attn_st, attn_ed);
    }
}

// Round 6
// 896.501 us; speedup vs baseline: 7.7513x; 1.2386x over previous
//
#include <hip/hip_runtime.h>
#include <math.h>

#define B_   8
#define L_   1024
#define D_   768
#define R_   16
#define NSP  4
#define NREL 33
#define NQ   896    // valid qw cols: 768 q + 33 rel (padded to 1024 in GEMM)

typedef __attribute__((ext_vector_type(8))) short bf16x8;
typedef __attribute__((ext_vector_type(4))) float f32x4;
typedef __attribute__((address_space(1))) const void gv_t;
typedef __attribute__((address_space(3))) void sv_t;

__device__ __forceinline__ unsigned short f2bf(float f) {
    unsigned int u = __float_as_uint(f);
    u += 0x7fff + ((u >> 16) & 1);          // RNE
    return (unsigned short)(u >> 16);
}
__device__ __forceinline__ float bf2f(unsigned short s) {
    return __uint_as_float(((unsigned int)s) << 16);
}

struct PSet {
    const unsigned short* A0;
    const unsigned short* B0;
    const unsigned short* A1;   // dual-K phase 2
    const unsigned short* B1;
    const float*          bias;
    const unsigned short* addend;
    void*                 Cout;
    float*                qrel;
    long                  mValid;
    int                   relu;
};
struct PSet4 { PSet s[4]; };

// ===========================================================================
// 8-phase 256x256 MFMA GEMM (T2+T3+T4+T5). BK=64, 8 waves (2Mx4N), 512 thr.
// LDS 128 KiB: [dbuf][A/B][256*64] bf16, st_16x32 XOR-swizzle on reads,
// inverse-swizzled global source, linear global_load_lds dest.
// Counted vmcnt(4) once per K-tile. Dual-K: K = K0(A0,B0) ++ K1(A1,B1).
// MODE 0: bf16 C = relu?((acc + bias[col] + addend)*scale)
// MODE 1: scores -> fp32 out[(m*NSP+it)*L+col] + qrel gather + mask
// MODE 3: qw-proj: col<768 -> bf16 C; col in [768,801) -> f32 qrel
template<int MODE>
__global__ __launch_bounds__(512, 2) void k_mfma8(
    PSet4 ps,
    long aS0, long bS0, long bB0, int bR0, int K0,
    long aS1, long bS1, int K1,
    float scale, long cStride,
    const int* __restrict__ spw, const int* __restrict__ srcm,
    const int* __restrict__ attm, int it)
{
    PSet p = ps.s[blockIdx.z];
    const long row0 = (long)blockIdx.y * 256;
    const int  col0 = blockIdx.x * 256;

    __shared__ unsigned short lds[2][2][256 * 64];   // 128 KiB

    const int tid  = threadIdx.x;
    const int lane = tid & 63;
    const int wave = tid >> 6;          // 0..7
    const int wr = wave >> 2;           // 0..1  (M half)
    const int wc = wave & 3;            // 0..3  (N quarter)
    const int lq = lane >> 4, lr = lane & 15;

    const unsigned short* Bb0 = p.B0 + (row0 / bR0) * bB0;

    const int NT0 = K0 / 64;
    const int NT  = NT0 + K1 / 64;

    f32x4 acc[8][4];
#pragma unroll
    for (int m = 0; m < 8; ++m)
#pragma unroll
        for (int n = 0; n < 4; ++n) acc[m][n] = (f32x4)0.f;

    // stage one half-tile (16 KiB): linear LDS dest, pre-swizzled global src
    auto stageHalf = [&](int tt, int side, int h) {
        if (tt >= NT) return;
        const unsigned short* src; long stride; int k0;
        if (tt < NT0) { src = side ? Bb0  : p.A0; stride = side ? bS0 : aS0; k0 = tt * 64; }
        else          { src = side ? p.B1 : p.A1; stride = side ? bS1 : aS1; k0 = (tt - NT0) * 64; }
        const long base = side ? (long)col0 : row0;
        unsigned short* dst = &lds[tt & 1][side][h * 8192];
#pragma unroll
        for (int j = 0; j < 2; ++j) {
            const int r = j * 64 + wave * 8 + (lane >> 3);
            const int csrc = ((lane & 7) * 8) ^ (((r >> 2) & 1) << 4);
            const unsigned short* g = src + (base + h * 128 + r) * stride + k0 + csrc;
            __builtin_amdgcn_global_load_lds((gv_t*)g,
                (sv_t*)(dst + j * 4096 + wave * 512), 16, 0, 0);
        }
    };
    // swizzled fragment read
    auto rd = [&](int bt, int side, int r, int ks) -> bf16x8 {
        const int idx = r * 64 + (((ks << 5) | (lq << 3)) ^ (((r >> 2) & 1) << 4));
        return *(const bf16x8*)&lds[bt][side][idx];
    };

    // ---- prologue: tile0 (4 halves) + tile1 B halves; confirm tile0
    stageHalf(0, 0, 0); stageHalf(0, 0, 1);
    stageHalf(0, 1, 0); stageHalf(0, 1, 1);
    stageHalf(1, 1, 0); stageHalf(1, 1, 1);
    if (1 < NT) asm volatile("s_waitcnt vmcnt(4)" ::: "memory");
    else        asm volatile("s_waitcnt vmcnt(0)" ::: "memory");
    __builtin_amdgcn_s_barrier();

    bf16x8 af[4][2], bfr[4][2];

    for (int t = 0; t < NT; ++t) {
        const int bt = t & 1;
        // ---------- phase 1: read A m0-3 + B n0-1; stage (t+1).A0
#pragma unroll
        for (int mf = 0; mf < 4; ++mf)
#pragma unroll
            for (int ks = 0; ks < 2; ++ks)
                af[mf][ks] = rd(bt, 0, wr * 128 + mf * 16 + lr, ks);
#pragma unroll
        for (int nf = 0; nf < 2; ++nf)
#pragma unroll
            for (int ks = 0; ks < 2; ++ks)
                bfr[nf][ks] = rd(bt, 1, wc * 64 + nf * 16 + lr, ks);
        stageHalf(t + 1, 0, 0);
        __builtin_amdgcn_s_barrier();
        asm volatile("s_waitcnt lgkmcnt(0)" ::: "memory");
        __builtin_amdgcn_sched_barrier(0);
        __builtin_amdgcn_s_setprio(1);
#pragma unroll
        for (int nf = 0; nf < 2; ++nf)
#pragma unroll
            for (int mf = 0; mf < 4; ++mf)
#pragma unroll
                for (int ks = 0; ks < 2; ++ks)
                    acc[mf][nf] = __builtin_amdgcn_mfma_f32_16x16x32_bf16(
                        af[mf][ks], bfr[nf][ks], acc[mf][nf], 0, 0, 0);
        __builtin_amdgcn_s_setprio(0);
        __builtin_amdgcn_s_barrier();
        // ---------- phase 2: read B n2-3; stage (t+1).A1
#pragma unroll
        for (int nf = 2; nf < 4; ++nf)
#pragma unroll
            for (int ks = 0; ks < 2; ++ks)
                bfr[nf][ks] = rd(bt, 1, wc * 64 + nf * 16 + lr, ks);
        stageHalf(t + 1, 0, 1);
        __builtin_amdgcn_s_barrier();
        asm volatile("s_waitcnt lgkmcnt(0)" ::: "memory");
        __builtin_amdgcn_sched_barrier(0);
        __builtin_amdgcn_s_setprio(1);
#pragma unroll
        for (int nf = 2; nf < 4; ++nf)
#pragma unroll
            for (int mf = 0; mf < 4; ++mf)
#pragma unroll
                for (int ks = 0; ks < 2; ++ks)
                    acc[mf][nf] = __builtin_amdgcn_mfma_f32_16x16x32_bf16(
                        af[mf][ks], bfr[nf][ks], acc[mf][nf], 0, 0, 0);
        __builtin_amdgcn_s_setprio(0);
        __builtin_amdgcn_s_barrier();
        // ---------- phase 3: read A m4-7; stage (t+2).B0
#pragma unroll
        for (int mf = 0; mf < 4; ++mf)
#pragma unroll
            for (int ks = 0; ks < 2; ++ks)
                af[mf][ks] = rd(bt, 0, wr * 128 + 64 + mf * 16 + lr, ks);
        stageHalf(t + 2, 1, 0);
        __builtin_amdgcn_s_barrier();
        asm volatile("s_waitcnt lgkmcnt(0)" ::: "memory");
        __builtin_amdgcn_sched_barrier(0);
        __builtin_amdgcn_s_setprio(1);
#pragma unroll
        for (int nf = 0; nf < 2; ++nf)
#pragma unroll
            for (int mf = 0; mf < 4; ++mf)
#pragma unroll
                for (int ks = 0; ks < 2; ++ks)
                    acc[4 + mf][nf] = __builtin_amdgcn_mfma_f32_16x16x32_bf16(
                        af[mf][ks], bfr[nf][ks], acc[4 + mf][nf], 0, 0, 0);
        __builtin_amdgcn_s_setprio(0);
        __builtin_amdgcn_s_barrier();
        // ---------- phase 4: stage (t+2).B1; counted vmcnt; MFMA m4-7 x n2-3
        stageHalf(t + 2, 1, 1);
        if (t + 2 < NT) asm volatile("s_waitcnt vmcnt(4)" ::: "memory");
        else            asm volatile("s_waitcnt vmcnt(0)" ::: "memory");
        __builtin_amdgcn_s_barrier();
        __builtin_amdgcn_sched_barrier(0);
        __builtin_amdgcn_s_setprio(1);
#pragma unroll
        for (int nf = 2; nf < 4; ++nf)
#pragma unroll
            for (int mf = 0; mf < 4; ++mf)
#pragma unroll
                for (int ks = 0; ks < 2; ++ks)
                    acc[4 + mf][nf] = __builtin_amdgcn_mfma_f32_16x16x32_bf16(
                        af[mf][ks], bfr[nf][ks], acc[4 + mf][nf], 0, 0, 0);
        __builtin_amdgcn_s_setprio(0);
        __builtin_amdgcn_s_barrier();
    }

    // ---------------- epilogue ----------------
    if (MODE == 0) {
        unsigned short* C = (unsigned short*)p.Cout;
#pragma unroll
        for (int nf = 0; nf < 4; ++nf) {
            const int col = col0 + wc * 64 + nf * 16 + lr;
            const float bc = p.bias ? p.bias[col] : 0.f;
#pragma unroll
            for (int mf = 0; mf < 8; ++mf) {
#pragma unroll
                for (int rr = 0; rr < 4; ++rr) {
                    const long row = row0 + wr * 128 + mf * 16 + lq * 4 + rr;
                    float v = acc[mf][nf][rr] + bc;
                    if (p.addend) v += bf2f(p.addend[row * cStride + col]);
                    v *= scale;
                    if (p.relu) v = fmaxf(v, 0.f);
                    C[row * cStride + col] = f2bf(v);
                }
            }
        }
    } else if (MODE == 1) {
        float* C = (float*)p.Cout;
        const float* qrel = p.qrel;
        const int b = (int)(row0 >> 10);
        int amv[4];
#pragma unroll
        for (int nf = 0; nf < 4; ++nf)
            amv[nf] = attm[b * L_ + col0 + wc * 64 + nf * 16 + lr];
#pragma unroll
        for (int mf = 0; mf < 8; ++mf) {
#pragma unroll
            for (int rr = 0; rr < 4; ++rr) {
                const long mg = row0 + wr * 128 + mf * 16 + lq * 4 + rr;
                const int ql = (int)(mg & (L_ - 1));
                const bool rowAct = (it < spw[mg]) && (srcm[mg] != 0);
                const float* qr = qrel + mg * NREL;
#pragma unroll
                for (int nf = 0; nf < 4; ++nf) {
                    const int col = col0 + wc * 64 + nf * 16 + lr;
                    int dr = col - ql; dr = dr < -R_ ? -R_ : (dr > R_ ? R_ : dr);
                    const float v = (rowAct && amv[nf]) ? (acc[mf][nf][rr] + qr[dr + R_]) : -1e18f;
                    C[(mg * NSP + it) * L_ + col] = v;
                }
            }
        }
    } else {   // MODE 3
        unsigned short* Cq = (unsigned short*)p.Cout;
        float* qout = p.qrel;
#pragma unroll
        for (int nf = 0; nf < 4; ++nf) {
            const int col = col0 + wc * 64 + nf * 16 + lr;
            const float bc = (col < NQ) ? p.bias[col] : 0.f;
            if (col < D_) {
#pragma unroll
                for (int mf = 0; mf < 8; ++mf)
#pragma unroll
                    for (int rr = 0; rr < 4; ++rr) {
                        const long row = row0 + wr * 128 + mf * 16 + lq * 4 + rr;
                        Cq[row * (long)D_ + col] = f2bf((acc[mf][nf][rr] + bc) * scale);
                    }
            } else if (col - D_ < NREL) {
                const int rc = col - D_;
#pragma unroll
                for (int mf = 0; mf < 8; ++mf)
#pragma unroll
                    for (int rr = 0; rr < 4; ++rr) {
                        const long row = row0 + wr * 128 + mf * 16 + lq * 4 + rr;
                        qout[row * NREL + rc] = (acc[mf][nf][rr] + bc) * scale;
                    }
            }
        }
    }
}

// ===========================================================================
// Legacy 2-phase 128x128 kernel (prep-only: Gt / Wqrel, small M)
__global__ __launch_bounds__(256) void k_mfma_prep(
    PSet4 ps, long aS0, long bS0, int K0, long cStride)
{
    PSet p = ps.s[blockIdx.z];
    const long row0 = (long)blockIdx.y * 128;
    if (row0 >= p.mValid) return;
    const int col0 = blockIdx.x * 128;

    __shared__ unsigned short As[2][128 * 32];
    __shared__ unsigned short Bs[2][128 * 32];
    const int tid  = threadIdx.x;
    const int lane = tid & 63;
    const int wave = tid >> 6;
    const int wr = wave >> 1, wc = wave & 1;
    const int lq = lane >> 4, lr = lane & 15;
    const int sr = lane >> 2;
    const int sc = (lane & 3) * 8;

    f32x4 acc[4][4];
#pragma unroll
    for (int m = 0; m < 4; ++m)
#pragma unroll
        for (int n = 0; n < 4; ++n) acc[m][n] = (f32x4)0.f;

    const int NT = K0 / 32;
    auto stage = [&](int t, int buf) {
        const int k0 = t * 32;
#pragma unroll
        for (int j = 0; j < 2; ++j) {
            const int c = wave + j * 4;
            const unsigned short* ga = p.A0 + (row0 + c * 16 + sr) * aS0 + k0 + sc;
            const unsigned short* gb = p.B0 + (long)(col0 + c * 16 + sr) * bS0 + k0 + sc;
            __builtin_amdgcn_global_load_lds((gv_t*)ga, (sv_t*)&As[buf][c * 512], 16, 0, 0);
            __builtin_amdgcn_global_load_lds((gv_t*)gb, (sv_t*)&Bs[buf][c * 512], 16, 0, 0);
        }
    };
    stage(0, 0);
    asm volatile("s_waitcnt vmcnt(0)" ::: "memory");
    __builtin_amdgcn_s_barrier();
    int cur = 0;
    for (int t = 0; t < NT; ++t) {
        if (t + 1 < NT) stage(t + 1, cur ^ 1);
        bf16x8 a4[4], b4[4];
#pragma unroll
        for (int m = 0; m < 4; ++m)
            a4[m] = *(const bf16x8*)&As[cur][(wr * 64 + m * 16 + lr) * 32 + lq * 8];
#pragma unroll
        for (int n = 0; n < 4; ++n)
            b4[n] = *(const bf16x8*)&Bs[cur][(wc * 64 + n * 16 + lr) * 32 + lq * 8];
#pragma unroll
        for (int m = 0; m < 4; ++m)
#pragma unroll
            for (int n = 0; n < 4; ++n)
                acc[m][n] = __builtin_amdgcn_mfma_f32_16x16x32_bf16(a4[m], b4[n], acc[m][n], 0, 0, 0);
        asm volatile("s_waitcnt vmcnt(0)" ::: "memory");
        __builtin_amdgcn_s_barrier();
        cur ^= 1;
    }
    unsigned short* C = (unsigned short*)p.Cout;
#pragma unroll
    for (int n = 0; n < 4; ++n) {
        const int col = col0 + wc * 64 + n * 16 + lr;
#pragma unroll
        for (int m = 0; m < 4; ++m)
#pragma unroll
            for (int r = 0; r < 4; ++r) {
                const long row = row0 + wr * 64 + m * 16 + lq * 4 + r;
                C[row * cStride + col] = f2bf(acc[m][n][r]);
            }
    }
}

// ---------------------------------------------------------------------------
struct Zero4 { float4* p[4]; long n4[4]; };
__global__ __launch_bounds__(256) void k_zero4(Zero4 z)
{
    long g = (long)blockIdx.x * 256 + threadIdx.x;
#pragma unroll
    for (int s = 0; s < 4; ++s) {
        if (g < z.n4[s]) {
            float4 v; v.x = v.y = v.z = v.w = 0.f;
            z.p[s][g] = v;
            return;
        }
        g -= z.n4[s];
    }
}

struct Cvt8 { const float* src[8]; unsigned short* dst[8]; long n4[8]; };
__global__ __launch_bounds__(256) void k_cvt8(Cvt8 c)
{
    long g = (long)blockIdx.x * 256 + threadIdx.x;
#pragma unroll
    for (int s = 0; s < 8; ++s) {
        if (g < c.n4[s]) {
            const float4 v = ((const float4*)c.src[s])[g];
            ushort4 o; o.x = f2bf(v.x); o.y = f2bf(v.y); o.z = f2bf(v.z); o.w = f2bf(v.w);
            ((ushort4*)c.dst[s])[g] = o;
            return;
        }
        g -= c.n4[s];
    }
}

__global__ __launch_bounds__(256) void k_transpose(
    const float* __restrict__ in, unsigned short* __restrict__ out, int rows, int cols)
{
    __shared__ float t[32][33];
    const long zo = (long)blockIdx.z * rows * cols;
    const int c0 = blockIdx.x * 32, r0 = blockIdx.y * 32;
    const int tx = threadIdx.x & 31, ty = threadIdx.x >> 5;
#pragma unroll
    for (int i = 0; i < 32; i += 8)
        t[ty + i][tx] = in[zo + (long)(r0 + ty + i) * cols + c0 + tx];
    __syncthreads();
#pragma unroll
    for (int i = 0; i < 32; i += 8)
        out[zo + (long)(c0 + ty + i) * rows + r0 + tx] = f2bf(t[tx][ty + i]);
}

__global__ __launch_bounds__(256) void k_transpose_bf(
    const unsigned short* __restrict__ in, unsigned short* __restrict__ out,
    int rows, int cols)
{
    __shared__ unsigned short t[32][33];
    const long zo = (long)blockIdx.z * rows * cols;
    const int c0 = blockIdx.x * 32, r0 = blockIdx.y * 32;
    const int tx = threadIdx.x & 31, ty = threadIdx.x >> 5;
#pragma unroll
    for (int i = 0; i < 32; i += 8)
        t[ty + i][tx] = in[zo + (long)(r0 + ty + i) * cols + c0 + tx];
    __syncthreads();
#pragma unroll
    for (int i = 0; i < 32; i += 8)
        out[zo + (long)(c0 + ty + i) * rows + r0 + tx] = t[tx][ty + i];
}

// ---------------------------------------------------------------------------
__global__ __launch_bounds__(128) void k_biasq(
    const float* __restrict__ bq0, const float* __restrict__ bq1,
    const float* __restrict__ wk0, const float* __restrict__ wk1,
    const float* __restrict__ rel0, const float* __restrict__ rel1,
    float* __restrict__ out0, float* __restrict__ out1)
{
    const int z = blockIdx.y;
    const float* bq  = z ? bq1  : bq0;
    const float* wk  = z ? wk1  : wk0;
    const float* rel = z ? rel1 : rel0;
    float* out       = z ? out1 : out0;
    const int i = blockIdx.x * 128 + threadIdx.x;
    if (i >= NQ) return;
    float a = 0.f;
    if (i < D_) {
        const float* w = wk + (long)i * D_;
        for (int e = 0; e < D_; ++e) a += bq[e] * w[e];
    } else if (i - D_ < NREL) {
        const float* w = rel + (long)(i - D_) * D_;
        for (int e = 0; e < D_; ++e) a += bq[e] * w[e];
    }
    out[i] = a;
}

// ---------------------------------------------------------------------------
__global__ __launch_bounds__(256) void k_softmax(
    float* __restrict__ base0, float* __restrict__ base1,
    unsigned short* __restrict__ bf0, unsigned short* __restrict__ bf1)
{
    float* base = blockIdx.y ? base1 : base0;
    unsigned short* bfout = blockIdx.y ? bf1 : bf0;
    const long m = blockIdx.x;
    float* p = base + m * (long)(NSP * L_);
    const int t = threadIdx.x;
    float4 v = *reinterpret_cast<float4*>(p + 4 * t);
    float mx = fmaxf(fmaxf(v.x, v.y), fmaxf(v.z, v.w));
#pragma unroll
    for (int o = 32; o > 0; o >>= 1) mx = fmaxf(mx, __shfl_xor(mx, o, 64));
    __shared__ float redm[4];
    __shared__ float reds[4];
    const int wave = t >> 6;
    if ((t & 63) == 0) redm[wave] = mx;
    __syncthreads();
    mx = fmaxf(fmaxf(redm[0], redm[1]), fmaxf(redm[2], redm[3]));
    v.x = expf(v.x - mx); v.y = expf(v.y - mx); v.z = expf(v.z - mx); v.w = expf(v.w - mx);
    float s = v.x + v.y + v.z + v.w;
#pragma unroll
    for (int o = 32; o > 0; o >>= 1) s += __shfl_xor(s, o, 64);
    if ((t & 63) == 0) reds[wave] = s;
    __syncthreads();
    s = reds[0] + reds[1] + reds[2] + reds[3];
    const float inv = 1.0f / s;
    v.x *= inv; v.y *= inv; v.z *= inv; v.w *= inv;
    *reinterpret_cast<float4*>(p + 4 * t) = v;
    ushort4 o; o.x = f2bf(v.x); o.y = f2bf(v.y); o.z = f2bf(v.z); o.w = f2bf(v.w);
    *(ushort4*)&bfout[m * (long)L_ + 4 * t] = o;
}

// ---------------------------------------------------------------------------
__global__ __launch_bounds__(256) void k_count(const int* __restrict__ attm, float* __restrict__ counts)
{
    const int b = blockIdx.x, t = threadIdx.x;
    int c = 0;
    for (int k = t; k < L_; k += 256) c += (attm[b * L_ + k] != 0);
#pragma unroll
    for (int o = 32; o > 0; o >>= 1) c += __shfl_xor(c, o, 64);
    __shared__ int red[4];
    if ((t & 63) == 0) red[t >> 6] = c;
    __syncthreads();
    if (t == 0) counts[b] = (float)(red[0] + red[1] + red[2] + red[3]);
}

__global__ __launch_bounds__(256) void k_batchsum(
    const float* __restrict__ hid, const int* __restrict__ attm, float* __restrict__ pooled)
{
    const int b = blockIdx.x;
    const int d = blockIdx.y * 256 + threadIdx.x;
    const int k0 = blockIdx.z * 128;
    const float* hb = hid + (long)b * L_ * D_;
    float acc = 0.f;
    for (int k = k0; k < k0 + 128; ++k)
        acc += attm[b * L_ + k] ? hb[(long)k * D_ + d] : 0.f;
    atomicAdd(&pooled[b * D_ + d], acc);
}

__global__ __launch_bounds__(256) void k_pw2(
    const float* __restrict__ pooled, const float* __restrict__ W_sp, float* __restrict__ pw2)
{
    const int b = blockIdx.x;
    const int n = blockIdx.y * 256 + threadIdx.x;
    const int d0 = blockIdx.z * 96;
    float acc = 0.f;
    for (int d = d0; d < d0 + 96; ++d)
        acc += pooled[b * D_ + d] * W_sp[(long)(D_ + d) * D_ + n];
    atomicAdd(&pw2[b * D_ + n], acc);
}

__global__ __launch_bounds__(256) void k_addend0m(
    const float* __restrict__ pw2, const float* __restrict__ counts,
    const int* __restrict__ srcm, const int* __restrict__ spw,
    unsigned short* __restrict__ out, float* __restrict__ outM)
{
    const long idx = (long)blockIdx.x * 256 + threadIdx.x;
    const int d = (int)(idx % D_);
    const long m = idx / D_;
    const int b = (int)(m >> 10);
    const float inv = 1.0f / fmaxf(counts[b], 1.0f);
    out[idx] = f2bf(srcm[m] ? pw2[b * D_ + d] * inv : 0.0f);
    if (idx < (long)B_ * L_ * NSP)
        outM[idx] = ((int)(idx & 3) < spw[idx >> 2]) ? 1.0f : 0.0f;
}

// ---------------------------------------------------------------------------
extern "C" void kernel_launch(void* const* d_in, const int* in_sizes, int n_in,
                              void* d_out, int out_size, void* d_ws, size_t ws_size,
                              hipStream_t stream)
{
    (void)in_sizes; (void)n_in; (void)out_size; (void)ws_size;
    const float* hid     = (const float*)d_in[0];
    const float* src_hid = (const float*)d_in[1];
    const int*   spw     = (const int*)d_in[2];
    const int*   attm    = (const int*)d_in[3];
    const int*   srcm    = (const int*)d_in[4];
    const float* Wq_st = (const float*)d_in[6];
    const float* bq_st = (const float*)d_in[7];
    const float* Wk_st = (const float*)d_in[8];
    const float* rel_st= (const float*)d_in[10];
    const float* Wq_ed = (const float*)d_in[11];
    const float* bq_ed = (const float*)d_in[12];
    const float* Wk_ed = (const float*)d_in[13];
    const float* rel_ed= (const float*)d_in[15];
    const float* W_sp  = (const float*)d_in[16];
    const float* b_sp  = (const float*)d_in[17];

    float* out      = (float*)d_out;
    float* outSts   = out;
    float* outEds   = out + (long)B_ * L_ * NSP * L_;
    float* outMasks = outEds + (long)B_ * L_ * NSP * L_;

    const long S = (long)B_ * L_ * D_;
    const long DD = (long)D_ * D_;
    char* wsB = (char*)d_ws;
    auto take = [&](size_t bytes) -> char* {
        char* p = wsB; wsB += (bytes + 255) & ~(size_t)255; return p;
    };
    unsigned short* hid_bf   = (unsigned short*)take(S * 2);
    unsigned short* src_bf   = (unsigned short*)take(S * 2);
    unsigned short* h1a      = (unsigned short*)take(S * 2);
    unsigned short* h1b      = (unsigned short*)take(S * 2);
    unsigned short* h2a      = (unsigned short*)take(S * 2);
    unsigned short* h2b      = (unsigned short*)take(S * 2);
    unsigned short* tmpQst   = (unsigned short*)take(S * 2);
    unsigned short* tmpQed   = (unsigned short*)take(S * 2);
    unsigned short* tmpP     = (unsigned short*)take(S * 2);
    unsigned short* hidW2T   = (unsigned short*)take(S * 2);   // [B][D][L]
    unsigned short* add0     = (unsigned short*)take(S * 2);
    unsigned short* WqExtSt  = (unsigned short*)take((long)1024 * D_ * 2); // 768 Gt + 128 Wqrel + pad
    unsigned short* WqExtEd  = (unsigned short*)take((long)1024 * D_ * 2);
    unsigned short* W1T      = (unsigned short*)take(DD * 2);
    unsigned short* W2T      = (unsigned short*)take(DD * 2);
    unsigned short* WqBfSt   = (unsigned short*)take(DD * 2);
    unsigned short* WqBfEd   = (unsigned short*)take(DD * 2);
    unsigned short* WkBfSt   = (unsigned short*)take(DD * 2);
    unsigned short* WkBfEd   = (unsigned short*)take(DD * 2);
    unsigned short* relbst   = (unsigned short*)take((long)128 * D_ * 2);
    unsigned short* relbed   = (unsigned short*)take((long)128 * D_ * 2);
    unsigned short* attn_st  = (unsigned short*)take((long)B_ * L_ * L_ * 2);
    unsigned short* attn_ed  = (unsigned short*)take((long)B_ * L_ * L_ * 2);
    float* qrelbSt = (float*)take((long)B_ * L_ * NREL * 4);
    float* qrelbEd = (float*)take((long)B_ * L_ * NREL * 4);
    float* biasQst = (float*)take(NQ * 4);
    float* biasQed = (float*)take(NQ * 4);
    float* pooled  = (float*)take((long)B_ * D_ * 4);
    float* pw2     = (float*)take((long)B_ * D_ * 4);
    float* counts  = (float*)take(256);

    const float invs = 1.0f / sqrtf((float)D_);
    const long BB   = (long)L_ * D_;
    const int  NOB  = 1 << 30;
    const long MFULL = 1L << 40;

    PSet4 ps;
    auto set = [&](int i, const unsigned short* A0, const unsigned short* B0,
                   const unsigned short* A1, const unsigned short* B1,
                   const float* bias, const unsigned short* addend,
                   void* C, float* qr, long mValid, int relu) {
        ps.s[i] = PSet{A0, B0, A1, B1, bias, addend, C, qr, mValid, relu};
    };

    // ---- prep ----
    {
        Zero4 z;
        z.p[0] = (float4*)(relbst + (long)NREL * D_); z.n4[0] = (long)(128 - NREL) * D_ * 2 / 16;
        z.p[1] = (float4*)(relbed + (long)NREL * D_); z.n4[1] = (long)(128 - NREL) * D_ * 2 / 16;
        z.p[2] = (float4*)pooled;                     z.n4[2] = (long)B_ * D_ / 4;
        z.p[3] = (float4*)pw2;                        z.n4[3] = (long)B_ * D_ / 4;
        const long tot = z.n4[0] + z.n4[1] + z.n4[2] + z.n4[3];
        k_zero4<<<(int)((tot + 255) / 256), 256, 0, stream>>>(z);
    }
    {
        Cvt8 c;
        c.src[0] = hid;     c.dst[0] = hid_bf;  c.n4[0] = S / 4;
        c.src[1] = src_hid; c.dst[1] = src_bf;  c.n4[1] = S / 4;
        c.src[2] = Wq_st;   c.dst[2] = WqBfSt;  c.n4[2] = DD / 4;
        c.src[3] = Wq_ed;   c.dst[3] = WqBfEd;  c.n4[3] = DD / 4;
        c.src[4] = Wk_st;   c.dst[4] = WkBfSt;  c.n4[4] = DD / 4;
        c.src[5] = Wk_ed;   c.dst[5] = WkBfEd;  c.n4[5] = DD / 4;
        c.src[6] = rel_st;  c.dst[6] = relbst;  c.n4[6] = (long)NREL * D_ / 4;
        c.src[7] = rel_ed;  c.dst[7] = relbed;  c.n4[7] = (long)NREL * D_ / 4;
        long tot = 0; for (int i = 0; i < 8; ++i) tot += c.n4[i];
        k_cvt8<<<(int)((tot + 255) / 256), 256, 0, stream>>>(c);
    }
    k_transpose<<<dim3(D_ / 32, D_ / 32, 2), 256, 0, stream>>>(W_sp, W1T, D_, D_);
    k_biasq<<<dim3(NQ / 128, 2), 128, 0, stream>>>(bq_st, bq_ed, Wk_st, Wk_ed,
                                                   rel_st, rel_ed, biasQst, biasQed);
    k_count<<<B_, 256, 0, stream>>>(attm, counts);
    k_batchsum<<<dim3(B_, D_ / 256, 8), 256, 0, stream>>>(hid, attm, pooled);
    k_pw2<<<dim3(B_, D_ / 256, 8), 256, 0, stream>>>(pooled, W_sp, pw2);
    k_addend0m<<<(int)(S / 256), 256, 0, stream>>>(pw2, counts, srcm, spw, add0, outMasks);

    // ---- Gt (Wk.Wq^T) + Wqrel (rel.Wq^T), legacy 128^2 kernel, z=4 ----
    set(0, WkBfSt, WqBfSt, nullptr, nullptr, nullptr, nullptr, WqExtSt, nullptr, D_, 0);
    set(1, WkBfEd, WqBfEd, nullptr, nullptr, nullptr, nullptr, WqExtEd, nullptr, D_, 0);
    set(2, relbst, WqBfSt, nullptr, nullptr, nullptr, nullptr, WqExtSt + DD, nullptr, 128, 0);
    set(3, relbed, WqBfEd, nullptr, nullptr, nullptr, nullptr, WqExtEd + DD, nullptr, 128, 0);
    k_mfma_prep<<<dim3(D_ / 128, D_ / 128, 4), 256, 0, stream>>>(ps, D_, D_, D_, D_);

    // ---- it-0 concat (src@W1 + add0, relu) + hid@W2, 8-phase z=2 ----
    set(0, src_bf, W1T, nullptr, nullptr, b_sp, add0, h1a, nullptr, MFULL, 1);
    set(1, hid_bf, W2T, nullptr, nullptr, nullptr, nullptr, tmpP, nullptr, MFULL, 0);
    k_mfma8<0><<<dim3(D_ / 256, (B_ * L_) / 256, 2), 512, 0, stream>>>(
        ps, D_, D_, 0, NOB, D_, D_, D_, 0, 1.f, D_, nullptr, nullptr, nullptr, 0);
    k_transpose_bf<<<dim3(D_ / 32, L_ / 32, B_), 256, 0, stream>>>(tmpP, hidW2T, L_, D_);

    unsigned short* h1cur = h1a; unsigned short* h2cur = h1a;
    unsigned short* h1nxt = h1b; unsigned short* h2nxt = h2a;

    for (int it = 0; it < NSP; ++it) {
        if (it > 0) {
            // fused pooling+concat: attn@hidW2T (K=1024) + hcur@W1 (K=768)
            set(0, attn_st, hidW2T, h1cur, W1T, b_sp, nullptr, h1nxt, nullptr, MFULL, 1);
            set(1, attn_ed, hidW2T, h2cur, W1T, b_sp, nullptr, h2nxt, nullptr, MFULL, 1);
            k_mfma8<0><<<dim3(D_ / 256, (B_ * L_) / 256, 2), 512, 0, stream>>>(
                ps, L_, L_, BB, L_, L_, D_, D_, D_, 1.f, D_, nullptr, nullptr, nullptr, 0);
            h1cur = h1nxt; h2cur = h2nxt;
            h1nxt = (h1cur == h1a) ? h1b : h1a;
            h2nxt = (h2cur == h2a) ? h2b : h2a;
        }
        // fused qw-proj + qrel (N padded to 1024)
        set(0, h1cur, WqExtSt, nullptr, nullptr, biasQst, nullptr, tmpQst, qrelbSt, MFULL, 0);
        set(1, h2cur, WqExtEd, nullptr, nullptr, biasQed, nullptr, tmpQed, qrelbEd, MFULL, 0);
        k_mfma8<3><<<dim3(1024 / 256, (B_ * L_) / 256, 2), 512, 0, stream>>>(
            ps, D_, D_, 0, NOB, D_, D_, D_, 0, invs, D_, nullptr, nullptr, nullptr, 0);
        // scores: qw @ hid^T (B = hid_bf, batched)
        set(0, tmpQst, hid_bf, nullptr, nullptr, nullptr, nullptr, outSts, qrelbSt, MFULL, 0);
        set(1, tmpQed, hid_bf, nullptr, nullptr, nullptr, nullptr, outEds, qrelbEd, MFULL, 0);
        k_mfma8<1><<<dim3(L_ / 256, (B_ * L_) / 256, 2), 512, 0, stream>>>(
            ps, D_, D_, BB, L_, D_, D_, D_, 0, 1.f, 0, spw, srcm, attm, it);
        // softmax st+ed
        k_softmax<<<dim3(B_ * L_, 2), 256, 0, stream>>>(
            outSts + (long)it * L_, outEds + (long)it * L_, attn_st, attn_ed);
    }
}

// Round 7
// 818.085 us; speedup vs baseline: 8.4943x; 1.0959x over previous
//
#include <hip/hip_runtime.h>
#include <math.h>

#define B_   8
#define L_   1024
#define D_   768
#define R_   16
#define NSP  4
#define NREL 33

typedef __attribute__((ext_vector_type(8))) short bf16x8;
typedef __attribute__((ext_vector_type(4))) float f32x4;
typedef __attribute__((address_space(1))) const void gv_t;
typedef __attribute__((address_space(3))) void sv_t;

__device__ __forceinline__ unsigned short f2bf(float f) {
    unsigned int u = __float_as_uint(f);
    u += 0x7fff + ((u >> 16) & 1);          // RNE
    return (unsigned short)(u >> 16);
}
__device__ __forceinline__ float bf2f(unsigned short s) {
    return __uint_as_float(((unsigned int)s) << 16);
}

struct PSet {
    const unsigned short* A0;
    const unsigned short* B0;
    const unsigned short* A1;   // dual-K phase 2
    const unsigned short* B1;
    const float*          bias;
    const unsigned short* addend;
    void*                 Cout;
    float*                qout;    // mode 2 output (fp32 qrel)
    const float*          bterm;   // mode 1 per-key bias
    long                  bB0;     // per-batch stride of B0 (0 = unbatched)
    long                  cStride;
    long                  mValid;  // prep kernel row guard
    float                 scale;
    int                   mode;    // 0=bf16 C, 1=scores, 2=qrel
    int                   relu;
    int                   nValid;  // early-exit when col0 >= nValid
};
struct PSet4 { PSet s[4]; };

// ===========================================================================
// 8-phase 256x256 MFMA GEMM (T2+T3+T4+T5). BK=64, 8 waves (2Mx4N), 512 thr.
// LDS 128 KiB dbuf, st_16x32 XOR-swizzle reads + inverse-swizzled global src,
// linear global_load_lds dest, counted vmcnt(4). Runtime per-z mode/epilogue.
__global__ __launch_bounds__(512, 2) void k_mfma8(
    PSet4 ps, long aS0, long bS0, int bR0, int K0,
    long aS1, long bS1, int K1,
    const int* __restrict__ spw, const int* __restrict__ srcm,
    const int* __restrict__ attm, int it)
{
    PSet p = ps.s[blockIdx.z];
    const int col0 = blockIdx.x * 256;
    if (col0 >= p.nValid) return;
    const long row0 = (long)blockIdx.y * 256;

    __shared__ unsigned short lds[2][2][256 * 64];   // 128 KiB

    const int tid  = threadIdx.x;
    const int lane = tid & 63;
    const int wave = tid >> 6;
    const int wr = wave >> 2;           // 0..1 (M half)
    const int wc = wave & 3;            // 0..3 (N quarter)
    const int lq = lane >> 4, lr = lane & 15;

    const unsigned short* Bb0 = p.B0 + (row0 / bR0) * p.bB0;

    const int NT0 = K0 / 64;
    const int NT  = NT0 + K1 / 64;

    f32x4 acc[8][4];
#pragma unroll
    for (int m = 0; m < 8; ++m)
#pragma unroll
        for (int n = 0; n < 4; ++n) acc[m][n] = (f32x4)0.f;

    auto stageHalf = [&](int tt, int side, int h) {
        if (tt >= NT) return;
        const unsigned short* src; long stride; int k0;
        if (tt < NT0) { src = side ? Bb0  : p.A0; stride = side ? bS0 : aS0; k0 = tt * 64; }
        else          { src = side ? p.B1 : p.A1; stride = side ? bS1 : aS1; k0 = (tt - NT0) * 64; }
        const long base = side ? (long)col0 : row0;
        unsigned short* dst = &lds[tt & 1][side][h * 8192];
#pragma unroll
        for (int j = 0; j < 2; ++j) {
            const int r = j * 64 + wave * 8 + (lane >> 3);
            const int csrc = ((lane & 7) * 8) ^ (((r >> 2) & 1) << 4);
            const unsigned short* g = src + (base + h * 128 + r) * stride + k0 + csrc;
            __builtin_amdgcn_global_load_lds((gv_t*)g,
                (sv_t*)(dst + j * 4096 + wave * 512), 16, 0, 0);
        }
    };
    auto rd = [&](int bt, int side, int r, int ks) -> bf16x8 {
        const int idx = r * 64 + (((ks << 5) | (lq << 3)) ^ (((r >> 2) & 1) << 4));
        return *(const bf16x8*)&lds[bt][side][idx];
    };

    stageHalf(0, 0, 0); stageHalf(0, 0, 1);
    stageHalf(0, 1, 0); stageHalf(0, 1, 1);
    stageHalf(1, 1, 0); stageHalf(1, 1, 1);
    if (1 < NT) asm volatile("s_waitcnt vmcnt(4)" ::: "memory");
    else        asm volatile("s_waitcnt vmcnt(0)" ::: "memory");
    __builtin_amdgcn_s_barrier();

    bf16x8 af[4][2], bfr[4][2];

    for (int t = 0; t < NT; ++t) {
        const int bt = t & 1;
        // phase 1: read A m0-3 + B n0-1; stage (t+1).A0
#pragma unroll
        for (int mf = 0; mf < 4; ++mf)
#pragma unroll
            for (int ks = 0; ks < 2; ++ks)
                af[mf][ks] = rd(bt, 0, wr * 128 + mf * 16 + lr, ks);
#pragma unroll
        for (int nf = 0; nf < 2; ++nf)
#pragma unroll
            for (int ks = 0; ks < 2; ++ks)
                bfr[nf][ks] = rd(bt, 1, wc * 64 + nf * 16 + lr, ks);
        stageHalf(t + 1, 0, 0);
        __builtin_amdgcn_s_barrier();
        asm volatile("s_waitcnt lgkmcnt(0)" ::: "memory");
        __builtin_amdgcn_sched_barrier(0);
        __builtin_amdgcn_s_setprio(1);
#pragma unroll
        for (int nf = 0; nf < 2; ++nf)
#pragma unroll
            for (int mf = 0; mf < 4; ++mf)
#pragma unroll
                for (int ks = 0; ks < 2; ++ks)
                    acc[mf][nf] = __builtin_amdgcn_mfma_f32_16x16x32_bf16(
                        af[mf][ks], bfr[nf][ks], acc[mf][nf], 0, 0, 0);
        __builtin_amdgcn_s_setprio(0);
        __builtin_amdgcn_s_barrier();
        // phase 2: read B n2-3; stage (t+1).A1
#pragma unroll
        for (int nf = 2; nf < 4; ++nf)
#pragma unroll
            for (int ks = 0; ks < 2; ++ks)
                bfr[nf][ks] = rd(bt, 1, wc * 64 + nf * 16 + lr, ks);
        stageHalf(t + 1, 0, 1);
        __builtin_amdgcn_s_barrier();
        asm volatile("s_waitcnt lgkmcnt(0)" ::: "memory");
        __builtin_amdgcn_sched_barrier(0);
        __builtin_amdgcn_s_setprio(1);
#pragma unroll
        for (int nf = 2; nf < 4; ++nf)
#pragma unroll
            for (int mf = 0; mf < 4; ++mf)
#pragma unroll
                for (int ks = 0; ks < 2; ++ks)
                    acc[mf][nf] = __builtin_amdgcn_mfma_f32_16x16x32_bf16(
                        af[mf][ks], bfr[nf][ks], acc[mf][nf], 0, 0, 0);
        __builtin_amdgcn_s_setprio(0);
        __builtin_amdgcn_s_barrier();
        // phase 3: read A m4-7; stage (t+2).B0
#pragma unroll
        for (int mf = 0; mf < 4; ++mf)
#pragma unroll
            for (int ks = 0; ks < 2; ++ks)
                af[mf][ks] = rd(bt, 0, wr * 128 + 64 + mf * 16 + lr, ks);
        stageHalf(t + 2, 1, 0);
        __builtin_amdgcn_s_barrier();
        asm volatile("s_waitcnt lgkmcnt(0)" ::: "memory");
        __builtin_amdgcn_sched_barrier(0);
        __builtin_amdgcn_s_setprio(1);
#pragma unroll
        for (int nf = 0; nf < 2; ++nf)
#pragma unroll
            for (int mf = 0; mf < 4; ++mf)
#pragma unroll
                for (int ks = 0; ks < 2; ++ks)
                    acc[4 + mf][nf] = __builtin_amdgcn_mfma_f32_16x16x32_bf16(
                        af[mf][ks], bfr[nf][ks], acc[4 + mf][nf], 0, 0, 0);
        __builtin_amdgcn_s_setprio(0);
        __builtin_amdgcn_s_barrier();
        // phase 4: stage (t+2).B1; counted vmcnt; MFMA m4-7 x n2-3
        stageHalf(t + 2, 1, 1);
        if (t + 2 < NT) asm volatile("s_waitcnt vmcnt(4)" ::: "memory");
        else            asm volatile("s_waitcnt vmcnt(0)" ::: "memory");
        __builtin_amdgcn_s_barrier();
        __builtin_amdgcn_sched_barrier(0);
        __builtin_amdgcn_s_setprio(1);
#pragma unroll
        for (int nf = 2; nf < 4; ++nf)
#pragma unroll
            for (int mf = 0; mf < 4; ++mf)
#pragma unroll
                for (int ks = 0; ks < 2; ++ks)
                    acc[4 + mf][nf] = __builtin_amdgcn_mfma_f32_16x16x32_bf16(
                        af[mf][ks], bfr[nf][ks], acc[4 + mf][nf], 0, 0, 0);
        __builtin_amdgcn_s_setprio(0);
        __builtin_amdgcn_s_barrier();
    }

    // ---------------- epilogue (runtime mode) ----------------
    if (p.mode == 0) {
        unsigned short* C = (unsigned short*)p.Cout;
#pragma unroll
        for (int nf = 0; nf < 4; ++nf) {
            const int col = col0 + wc * 64 + nf * 16 + lr;
            const float bc = p.bias ? p.bias[col] : 0.f;
#pragma unroll
            for (int mf = 0; mf < 8; ++mf) {
#pragma unroll
                for (int rr = 0; rr < 4; ++rr) {
                    const long row = row0 + wr * 128 + mf * 16 + lq * 4 + rr;
                    float v = acc[mf][nf][rr] + bc;
                    if (p.addend) v += bf2f(p.addend[row * p.cStride + col]);
                    v *= p.scale;
                    if (p.relu) v = fmaxf(v, 0.f);
                    C[row * p.cStride + col] = f2bf(v);
                }
            }
        }
    } else if (p.mode == 1) {
        float* C = (float*)p.Cout;
        const int b = (int)(row0 >> 10);
        int amv[4]; float btv[4];
#pragma unroll
        for (int nf = 0; nf < 4; ++nf) {
            const int col = col0 + wc * 64 + nf * 16 + lr;
            amv[nf] = attm[b * L_ + col];
            btv[nf] = p.bterm[b * L_ + col];
        }
#pragma unroll
        for (int mf = 0; mf < 8; ++mf) {
#pragma unroll
            for (int rr = 0; rr < 4; ++rr) {
                const long mg = row0 + wr * 128 + mf * 16 + lq * 4 + rr;
                const bool rowAct = (it < spw[mg]) && (srcm[mg] != 0);
#pragma unroll
                for (int nf = 0; nf < 4; ++nf) {
                    const int col = col0 + wc * 64 + nf * 16 + lr;
                    const float v = (rowAct && amv[nf]) ? (acc[mf][nf][rr] + btv[nf]) : -1e18f;
                    C[(mg * NSP + it) * L_ + col] = v;
                }
            }
        }
    } else {   // mode 2: qrel fp32 (col < NREL)
        float* qout = p.qout;
#pragma unroll
        for (int nf = 0; nf < 3; ++nf) {
            const int col = wc * 64 + nf * 16 + lr;
            if (col < NREL) {
                const float bc = p.bias[col];
#pragma unroll
                for (int mf = 0; mf < 8; ++mf)
#pragma unroll
                    for (int rr = 0; rr < 4; ++rr) {
                        const long row = row0 + wr * 128 + mf * 16 + lq * 4 + rr;
                        qout[row * NREL + col] = (acc[mf][nf][rr] + bc) * p.scale;
                    }
            }
        }
    }
}

// ===========================================================================
// 2-phase 128x128 kernel (prep-only: GtT / Wqrel, small M)
__global__ __launch_bounds__(256) void k_mfma_prep(
    PSet4 ps, long aS0, long bS0, int K0)
{
    PSet p = ps.s[blockIdx.z];
    const long row0 = (long)blockIdx.y * 128;
    if (row0 >= p.mValid) return;
    const int col0 = blockIdx.x * 128;

    __shared__ unsigned short As[2][128 * 32];
    __shared__ unsigned short Bs[2][128 * 32];
    const int tid  = threadIdx.x;
    const int lane = tid & 63;
    const int wave = tid >> 6;
    const int wr = wave >> 1, wc = wave & 1;
    const int lq = lane >> 4, lr = lane & 15;
    const int sr = lane >> 2;
    const int sc = (lane & 3) * 8;

    f32x4 acc[4][4];
#pragma unroll
    for (int m = 0; m < 4; ++m)
#pragma unroll
        for (int n = 0; n < 4; ++n) acc[m][n] = (f32x4)0.f;

    const int NT = K0 / 32;
    auto stage = [&](int t, int buf) {
        const int k0 = t * 32;
#pragma unroll
        for (int j = 0; j < 2; ++j) {
            const int c = wave + j * 4;
            const unsigned short* ga = p.A0 + (row0 + c * 16 + sr) * aS0 + k0 + sc;
            const unsigned short* gb = p.B0 + (long)(col0 + c * 16 + sr) * bS0 + k0 + sc;
            __builtin_amdgcn_global_load_lds((gv_t*)ga, (sv_t*)&As[buf][c * 512], 16, 0, 0);
            __builtin_amdgcn_global_load_lds((gv_t*)gb, (sv_t*)&Bs[buf][c * 512], 16, 0, 0);
        }
    };
    stage(0, 0);
    asm volatile("s_waitcnt vmcnt(0)" ::: "memory");
    __builtin_amdgcn_s_barrier();
    int cur = 0;
    for (int t = 0; t < NT; ++t) {
        if (t + 1 < NT) stage(t + 1, cur ^ 1);
        bf16x8 a4[4], b4[4];
#pragma unroll
        for (int m = 0; m < 4; ++m)
            a4[m] = *(const bf16x8*)&As[cur][(wr * 64 + m * 16 + lr) * 32 + lq * 8];
#pragma unroll
        for (int n = 0; n < 4; ++n)
            b4[n] = *(const bf16x8*)&Bs[cur][(wc * 64 + n * 16 + lr) * 32 + lq * 8];
#pragma unroll
        for (int m = 0; m < 4; ++m)
#pragma unroll
            for (int n = 0; n < 4; ++n)
                acc[m][n] = __builtin_amdgcn_mfma_f32_16x16x32_bf16(a4[m], b4[n], acc[m][n], 0, 0, 0);
        asm volatile("s_waitcnt vmcnt(0)" ::: "memory");
        __builtin_amdgcn_s_barrier();
        cur ^= 1;
    }
    unsigned short* C = (unsigned short*)p.Cout;
#pragma unroll
    for (int n = 0; n < 4; ++n) {
        const int col = col0 + wc * 64 + n * 16 + lr;
#pragma unroll
        for (int m = 0; m < 4; ++m)
#pragma unroll
            for (int r = 0; r < 4; ++r) {
                const long row = row0 + wr * 64 + m * 16 + lq * 4 + r;
                C[row * p.cStride + col] = f2bf(acc[m][n][r]);
            }
    }
}

// ---------------------------------------------------------------------------
struct Zero6 { float4* p[6]; long n4[6]; };
__global__ __launch_bounds__(256) void k_zero6(Zero6 z)
{
    long g = (long)blockIdx.x * 256 + threadIdx.x;
#pragma unroll
    for (int s = 0; s < 6; ++s) {
        if (g < z.n4[s]) {
            float4 v; v.x = v.y = v.z = v.w = 0.f;
            z.p[s][g] = v;
            return;
        }
        g -= z.n4[s];
    }
}

struct Cvt8 { const float* src[8]; unsigned short* dst[8]; long n4[8]; };
__global__ __launch_bounds__(256) void k_cvt8(Cvt8 c)
{
    long g = (long)blockIdx.x * 256 + threadIdx.x;
#pragma unroll
    for (int s = 0; s < 8; ++s) {
        if (g < c.n4[s]) {
            const float4 v = ((const float4*)c.src[s])[g];
            ushort4 o; o.x = f2bf(v.x); o.y = f2bf(v.y); o.z = f2bf(v.z); o.w = f2bf(v.w);
            ((ushort4*)c.dst[s])[g] = o;
            return;
        }
        g -= c.n4[s];
    }
}

__global__ __launch_bounds__(256) void k_transpose(
    const float* __restrict__ in, unsigned short* __restrict__ out, int rows, int cols)
{
    __shared__ float t[32][33];
    const long zo = (long)blockIdx.z * rows * cols;
    const int c0 = blockIdx.x * 32, r0 = blockIdx.y * 32;
    const int tx = threadIdx.x & 31, ty = threadIdx.x >> 5;
#pragma unroll
    for (int i = 0; i < 32; i += 8)
        t[ty + i][tx] = in[zo + (long)(r0 + ty + i) * cols + c0 + tx];
    __syncthreads();
#pragma unroll
    for (int i = 0; i < 32; i += 8)
        out[zo + (long)(c0 + ty + i) * rows + r0 + tx] = f2bf(t[tx][ty + i]);
}

__global__ __launch_bounds__(256) void k_transpose_bf(
    const unsigned short* __restrict__ in, unsigned short* __restrict__ out,
    int rows, int cols)
{
    __shared__ unsigned short t[32][33];
    const long zo = (long)blockIdx.z * rows * cols;
    const int c0 = blockIdx.x * 32, r0 = blockIdx.y * 32;
    const int tx = threadIdx.x & 31, ty = threadIdx.x >> 5;
#pragma unroll
    for (int i = 0; i < 32; i += 8)
        t[ty + i][tx] = in[zo + (long)(r0 + ty + i) * cols + c0 + tx];
    __syncthreads();
#pragma unroll
    for (int i = 0; i < 32; i += 8)
        out[zo + (long)(c0 + ty + i) * rows + r0 + tx] = t[tx][ty + i];
}

// ---------------------------------------------------------------------------
// biasQ[896]: [0..767] = bq.Wk[d,:]; [768+r] = bq.rel[r,:]
__global__ __launch_bounds__(128) void k_biasq(
    const float* __restrict__ bq0, const float* __restrict__ bq1,
    const float* __restrict__ wk0, const float* __restrict__ wk1,
    const float* __restrict__ rel0, const float* __restrict__ rel1,
    float* __restrict__ out0, float* __restrict__ out1)
{
    const int z = blockIdx.y;
    const float* bq  = z ? bq1  : bq0;
    const float* wk  = z ? wk1  : wk0;
    const float* rel = z ? rel1 : rel0;
    float* out       = z ? out1 : out0;
    const int i = blockIdx.x * 128 + threadIdx.x;
    if (i >= 896) return;
    float a = 0.f;
    if (i < D_) {
        const float* w = wk + (long)i * D_;
        for (int e = 0; e < D_; ++e) a += bq[e] * w[e];
    } else if (i - D_ < NREL) {
        const float* w = rel + (long)(i - D_) * D_;
        for (int e = 0; e < D_; ++e) a += bq[e] * w[e];
    }
    out[i] = a;
}

// bterm[m] = invs * sum_d biasQ[d] * hid[m,d]   (one wave per row)
__global__ __launch_bounds__(256) void k_bterm(
    const unsigned short* __restrict__ hid_bf,
    const float* __restrict__ biasQ0, const float* __restrict__ biasQ1,
    float* __restrict__ out0, float* __restrict__ out1, float invs)
{
    const float* biasQ = blockIdx.y ? biasQ1 : biasQ0;
    float* out = blockIdx.y ? out1 : out0;
    const long row = (long)blockIdx.x * 4 + (threadIdx.x >> 6);
    const int lane = threadIdx.x & 63;
    const unsigned short* h = hid_bf + row * D_;
    float a = 0.f;
    for (int d = lane * 4; d < D_; d += 256) {
        const ushort4 u = *(const ushort4*)&h[d];
        const float4 bq4 = *(const float4*)&biasQ[d];
        a += bf2f(u.x) * bq4.x + bf2f(u.y) * bq4.y + bf2f(u.z) * bq4.z + bf2f(u.w) * bq4.w;
    }
#pragma unroll
    for (int o = 32; o > 0; o >>= 1) a += __shfl_xor(a, o, 64);
    if (lane == 0) out[row] = a * invs;
}

// ---------------------------------------------------------------------------
// row softmax over L=1024 with fused rel-gather; + bf16 copy; y selects st/ed
__global__ __launch_bounds__(256) void k_softmax(
    float* __restrict__ base0, float* __restrict__ base1,
    unsigned short* __restrict__ bf0, unsigned short* __restrict__ bf1,
    const float* __restrict__ qr0, const float* __restrict__ qr1)
{
    float* base = blockIdx.y ? base1 : base0;
    unsigned short* bfout = blockIdx.y ? bf1 : bf0;
    const float* qrel = blockIdx.y ? qr1 : qr0;
    const long m = blockIdx.x;
    const int q = (int)(m & (L_ - 1));
    float* p = base + m * (long)(NSP * L_);
    const float* qrow = qrel + m * NREL;
    const int t = threadIdx.x;
    float4 v = *reinterpret_cast<float4*>(p + 4 * t);
    float* vv = (float*)&v;
#pragma unroll
    for (int j = 0; j < 4; ++j) {
        int dr = 4 * t + j - q;
        dr = dr < -R_ ? -R_ : (dr > R_ ? R_ : dr);
        vv[j] += qrow[dr + R_];     // absorbed exactly by -1e18 for masked cols
    }
    float mx = fmaxf(fmaxf(v.x, v.y), fmaxf(v.z, v.w));
#pragma unroll
    for (int o = 32; o > 0; o >>= 1) mx = fmaxf(mx, __shfl_xor(mx, o, 64));
    __shared__ float redm[4];
    __shared__ float reds[4];
    const int wave = t >> 6;
    if ((t & 63) == 0) redm[wave] = mx;
    __syncthreads();
    mx = fmaxf(fmaxf(redm[0], redm[1]), fmaxf(redm[2], redm[3]));
    v.x = expf(v.x - mx); v.y = expf(v.y - mx); v.z = expf(v.z - mx); v.w = expf(v.w - mx);
    float s = v.x + v.y + v.z + v.w;
#pragma unroll
    for (int o = 32; o > 0; o >>= 1) s += __shfl_xor(s, o, 64);
    if ((t & 63) == 0) reds[wave] = s;
    __syncthreads();
    s = reds[0] + reds[1] + reds[2] + reds[3];
    const float inv = 1.0f / s;
    v.x *= inv; v.y *= inv; v.z *= inv; v.w *= inv;
    *reinterpret_cast<float4*>(p + 4 * t) = v;
    ushort4 o; o.x = f2bf(v.x); o.y = f2bf(v.y); o.z = f2bf(v.z); o.w = f2bf(v.w);
    *(ushort4*)&bfout[m * (long)L_ + 4 * t] = o;
}

// ---------------------------------------------------------------------------
__global__ __launch_bounds__(256) void k_count(const int* __restrict__ attm, float* __restrict__ counts)
{
    const int b = blockIdx.x, t = threadIdx.x;
    int c = 0;
    for (int k = t; k < L_; k += 256) c += (attm[b * L_ + k] != 0);
#pragma unroll
    for (int o = 32; o > 0; o >>= 1) c += __shfl_xor(c, o, 64);
    __shared__ int red[4];
    if ((t & 63) == 0) red[t >> 6] = c;
    __syncthreads();
    if (t == 0) counts[b] = (float)(red[0] + red[1] + red[2] + red[3]);
}

__global__ __launch_bounds__(256) void k_batchsum(
    const float* __restrict__ hid, const int* __restrict__ attm, float* __restrict__ pooled)
{
    const int b = blockIdx.x;
    const int d = blockIdx.y * 256 + threadIdx.x;
    const int k0 = blockIdx.z * 128;
    const float* hb = hid + (long)b * L_ * D_;
    float acc = 0.f;
    for (int k = k0; k < k0 + 128; ++k)
        acc += attm[b * L_ + k] ? hb[(long)k * D_ + d] : 0.f;
    atomicAdd(&pooled[b * D_ + d], acc);
}

__global__ __launch_bounds__(256) void k_pw2(
    const float* __restrict__ pooled, const float* __restrict__ W_sp, float* __restrict__ pw2)
{
    const int b = blockIdx.x;
    const int n = blockIdx.y * 256 + threadIdx.x;
    const int d0 = blockIdx.z * 96;
    float acc = 0.f;
    for (int d = d0; d < d0 + 96; ++d)
        acc += pooled[b * D_ + d] * W_sp[(long)(D_ + d) * D_ + n];
    atomicAdd(&pw2[b * D_ + n], acc);
}

__global__ __launch_bounds__(256) void k_addend0m(
    const float* __restrict__ pw2, const float* __restrict__ counts,
    const int* __restrict__ srcm, const int* __restrict__ spw,
    unsigned short* __restrict__ out, float* __restrict__ outM)
{
    const long idx = (long)blockIdx.x * 256 + threadIdx.x;
    const int d = (int)(idx % D_);
    const long m = idx / D_;
    const int b = (int)(m >> 10);
    const float inv = 1.0f / fmaxf(counts[b], 1.0f);
    out[idx] = f2bf(srcm[m] ? pw2[b * D_ + d] * inv : 0.0f);
    if (idx < (long)B_ * L_ * NSP)
        outM[idx] = ((int)(idx & 3) < spw[idx >> 2]) ? 1.0f : 0.0f;
}

// ---------------------------------------------------------------------------
extern "C" void kernel_launch(void* const* d_in, const int* in_sizes, int n_in,
                              void* d_out, int out_size, void* d_ws, size_t ws_size,
                              hipStream_t stream)
{
    (void)in_sizes; (void)n_in; (void)out_size; (void)ws_size;
    const float* hid     = (const float*)d_in[0];
    const float* src_hid = (const float*)d_in[1];
    const int*   spw     = (const int*)d_in[2];
    const int*   attm    = (const int*)d_in[3];
    const int*   srcm    = (const int*)d_in[4];
    const float* Wq_st = (const float*)d_in[6];
    const float* bq_st = (const float*)d_in[7];
    const float* Wk_st = (const float*)d_in[8];
    const float* rel_st= (const float*)d_in[10];
    const float* Wq_ed = (const float*)d_in[11];
    const float* bq_ed = (const float*)d_in[12];
    const float* Wk_ed = (const float*)d_in[13];
    const float* rel_ed= (const float*)d_in[15];
    const float* W_sp  = (const float*)d_in[16];
    const float* b_sp  = (const float*)d_in[17];

    float* out      = (float*)d_out;
    float* outSts   = out;
    float* outEds   = out + (long)B_ * L_ * NSP * L_;
    float* outMasks = outEds + (long)B_ * L_ * NSP * L_;

    const long S = (long)B_ * L_ * D_;
    const long DD = (long)D_ * D_;
    char* wsB = (char*)d_ws;
    auto take = [&](size_t bytes) -> char* {
        char* p = wsB; wsB += (bytes + 255) & ~(size_t)255; return p;
    };
    unsigned short* hid_bf  = (unsigned short*)take(S * 2);
    unsigned short* src_bf  = (unsigned short*)take(S * 2);
    unsigned short* h1a     = (unsigned short*)take(S * 2);
    unsigned short* h1b     = (unsigned short*)take(S * 2);
    unsigned short* h2a     = (unsigned short*)take(S * 2);
    unsigned short* h2b     = (unsigned short*)take(S * 2);
    unsigned short* tmpP    = (unsigned short*)take(S * 2);
    unsigned short* hidW2T  = (unsigned short*)take(S * 2);   // [B][D][L]
    unsigned short* add0    = (unsigned short*)take(S * 2);
    unsigned short* hidGst  = (unsigned short*)take(S * 2);
    unsigned short* hidGed  = (unsigned short*)take(S * 2);
    unsigned short* GtTst   = (unsigned short*)take(DD * 2);
    unsigned short* GtTed   = (unsigned short*)take(DD * 2);
    unsigned short* W1T     = (unsigned short*)take(DD * 2);  // contiguous with W2T
    unsigned short* W2T     = (unsigned short*)take(DD * 2);
    unsigned short* WqBfSt  = (unsigned short*)take(DD * 2);
    unsigned short* WqBfEd  = (unsigned short*)take(DD * 2);
    unsigned short* WkBfSt  = (unsigned short*)take(DD * 2);
    unsigned short* WkBfEd  = (unsigned short*)take(DD * 2);
    unsigned short* relbst  = (unsigned short*)take((long)128 * D_ * 2);
    unsigned short* relbed  = (unsigned short*)take((long)128 * D_ * 2);
    unsigned short* WqrelSt = (unsigned short*)take((long)256 * D_ * 2);
    unsigned short* WqrelEd = (unsigned short*)take((long)256 * D_ * 2);
    unsigned short* attn_st = (unsigned short*)take((long)B_ * L_ * L_ * 2);
    unsigned short* attn_ed = (unsigned short*)take((long)B_ * L_ * L_ * 2);
    float* qrelbSt = (float*)take((long)B_ * L_ * NREL * 4);
    float* qrelbEd = (float*)take((long)B_ * L_ * NREL * 4);
    float* biasQst = (float*)take(896 * 4);
    float* biasQed = (float*)take(896 * 4);
    float* btermSt = (float*)take((long)B_ * L_ * 4);
    float* btermEd = (float*)take((long)B_ * L_ * 4);
    float* pooled  = (float*)take((long)B_ * D_ * 4);
    float* pw2     = (float*)take((long)B_ * D_ * 4);
    float* counts  = (float*)take(256);

    const float invs = 1.0f / sqrtf((float)D_);
    const long BB   = (long)L_ * D_;
    const int  NOB  = 1 << 30;

    PSet4 ps;
    auto clr = [&](int i) {
        ps.s[i] = PSet{nullptr,nullptr,nullptr,nullptr,nullptr,nullptr,nullptr,
                       nullptr,nullptr,0,0,1L<<40,1.f,0,0,1<<30};
    };

    // ---- prep ----
    {
        Zero6 z;
        z.p[0] = (float4*)(relbst + (long)NREL * D_);  z.n4[0] = (long)(128 - NREL) * D_ * 2 / 16;
        z.p[1] = (float4*)(relbed + (long)NREL * D_);  z.n4[1] = (long)(128 - NREL) * D_ * 2 / 16;
        z.p[2] = (float4*)(WqrelSt + (long)128 * D_);  z.n4[2] = (long)128 * D_ * 2 / 16;
        z.p[3] = (float4*)(WqrelEd + (long)128 * D_);  z.n4[3] = (long)128 * D_ * 2 / 16;
        z.p[4] = (float4*)pooled;                      z.n4[4] = (long)B_ * D_ / 4;
        z.p[5] = (float4*)pw2;                         z.n4[5] = (long)B_ * D_ / 4;
        long tot = 0; for (int i = 0; i < 6; ++i) tot += z.n4[i];
        k_zero6<<<(int)((tot + 255) / 256), 256, 0, stream>>>(z);
    }
    {
        Cvt8 c;
        c.src[0] = hid;     c.dst[0] = hid_bf;  c.n4[0] = S / 4;
        c.src[1] = src_hid; c.dst[1] = src_bf;  c.n4[1] = S / 4;
        c.src[2] = Wq_st;   c.dst[2] = WqBfSt;  c.n4[2] = DD / 4;
        c.src[3] = Wq_ed;   c.dst[3] = WqBfEd;  c.n4[3] = DD / 4;
        c.src[4] = Wk_st;   c.dst[4] = WkBfSt;  c.n4[4] = DD / 4;
        c.src[5] = Wk_ed;   c.dst[5] = WkBfEd;  c.n4[5] = DD / 4;
        c.src[6] = rel_st;  c.dst[6] = relbst;  c.n4[6] = (long)NREL * D_ / 4;
        c.src[7] = rel_ed;  c.dst[7] = relbed;  c.n4[7] = (long)NREL * D_ / 4;
        long tot = 0; for (int i = 0; i < 8; ++i) tot += c.n4[i];
        k_cvt8<<<(int)((tot + 255) / 256), 256, 0, stream>>>(c);
    }
    k_transpose<<<dim3(D_ / 32, D_ / 32, 2), 256, 0, stream>>>(W_sp, W1T, D_, D_);
    k_biasq<<<dim3(7, 2), 128, 0, stream>>>(bq_st, bq_ed, Wk_st, Wk_ed,
                                            rel_st, rel_ed, biasQst, biasQed);
    k_count<<<B_, 256, 0, stream>>>(attm, counts);
    k_batchsum<<<dim3(B_, D_ / 256, 8), 256, 0, stream>>>(hid, attm, pooled);
    k_pw2<<<dim3(B_, D_ / 256, 8), 256, 0, stream>>>(pooled, W_sp, pw2);
    k_addend0m<<<(int)(S / 256), 256, 0, stream>>>(pw2, counts, srcm, spw, add0, outMasks);
    k_bterm<<<dim3(B_ * L_ / 4, 2), 256, 0, stream>>>(hid_bf, biasQst, biasQed,
                                                      btermSt, btermEd, invs);

    // GtT (Wq.Wk^T) + Wqrel (rel.Wq^T), 2-phase 128^2 kernel, z=4
    for (int i = 0; i < 4; ++i) clr(i);
    ps.s[0].A0 = WqBfSt; ps.s[0].B0 = WkBfSt; ps.s[0].Cout = GtTst;   ps.s[0].cStride = D_; ps.s[0].mValid = D_;
    ps.s[1].A0 = WqBfEd; ps.s[1].B0 = WkBfEd; ps.s[1].Cout = GtTed;   ps.s[1].cStride = D_; ps.s[1].mValid = D_;
    ps.s[2].A0 = relbst; ps.s[2].B0 = WqBfSt; ps.s[2].Cout = WqrelSt; ps.s[2].cStride = D_; ps.s[2].mValid = 128;
    ps.s[3].A0 = relbed; ps.s[3].B0 = WqBfEd; ps.s[3].Cout = WqrelEd; ps.s[3].cStride = D_; ps.s[3].mValid = 128;
    k_mfma_prep<<<dim3(D_ / 128, D_ / 128, 4), 256, 0, stream>>>(ps, D_, D_, D_);

    // concat0 (src@W1+add0, relu) + hid@W2 + hidG st/ed : one z=4 8-phase dispatch
    for (int i = 0; i < 4; ++i) clr(i);
    ps.s[0].A0 = src_bf; ps.s[0].B0 = W1T;   ps.s[0].bias = b_sp; ps.s[0].addend = add0;
    ps.s[0].Cout = h1a;  ps.s[0].cStride = D_; ps.s[0].relu = 1; ps.s[0].nValid = D_;
    ps.s[1].A0 = hid_bf; ps.s[1].B0 = W2T;   ps.s[1].Cout = tmpP;   ps.s[1].cStride = D_; ps.s[1].nValid = D_;
    ps.s[2].A0 = hid_bf; ps.s[2].B0 = GtTst; ps.s[2].Cout = hidGst; ps.s[2].cStride = D_; ps.s[2].scale = invs; ps.s[2].nValid = D_;
    ps.s[3].A0 = hid_bf; ps.s[3].B0 = GtTed; ps.s[3].Cout = hidGed; ps.s[3].cStride = D_; ps.s[3].scale = invs; ps.s[3].nValid = D_;
    k_mfma8<<<dim3(D_ / 256, (B_ * L_) / 256, 4), 512, 0, stream>>>(
        ps, D_, D_, NOB, D_, D_, D_, 0, nullptr, nullptr, nullptr, 0);
    k_transpose_bf<<<dim3(D_ / 32, L_ / 32, B_), 256, 0, stream>>>(tmpP, hidW2T, L_, D_);

    unsigned short* h1cur = h1a; unsigned short* h2cur = h1a;
    unsigned short* h1nxt = h1b; unsigned short* h2nxt = h2a;

    for (int it = 0; it < NSP; ++it) {
        if (it > 0) {
            // fused pooling+concat: attn@hidW2T (K=1024) + hcur@W1 (K=768)
            for (int i = 0; i < 4; ++i) clr(i);
            ps.s[0].A0 = attn_st; ps.s[0].B0 = hidW2T; ps.s[0].A1 = h1cur; ps.s[0].B1 = W1T;
            ps.s[0].bias = b_sp; ps.s[0].Cout = h1nxt; ps.s[0].cStride = D_;
            ps.s[0].relu = 1; ps.s[0].bB0 = (long)D_ * L_; ps.s[0].nValid = D_;
            ps.s[1] = ps.s[0];
            ps.s[1].A0 = attn_ed; ps.s[1].A1 = h2cur; ps.s[1].Cout = h2nxt;
            k_mfma8<<<dim3(D_ / 256, (B_ * L_) / 256, 2), 512, 0, stream>>>(
                ps, L_, L_, L_, L_, D_, D_, D_, nullptr, nullptr, nullptr, 0);
            h1cur = h1nxt; h2cur = h2nxt;
            h1nxt = (h1cur == h1a) ? h1b : h1a;
            h2nxt = (h2cur == h2a) ? h2b : h2a;
        }
        // fused scores (z0,z1) + qrel (z2,z3) — qrel consumed later by softmax
        for (int i = 0; i < 4; ++i) clr(i);
        ps.s[0].A0 = h1cur; ps.s[0].B0 = hidGst; ps.s[0].Cout = outSts;
        ps.s[0].bterm = btermSt; ps.s[0].bB0 = BB; ps.s[0].mode = 1; ps.s[0].nValid = L_;
        ps.s[1].A0 = h2cur; ps.s[1].B0 = hidGed; ps.s[1].Cout = outEds;
        ps.s[1].bterm = btermEd; ps.s[1].bB0 = BB; ps.s[1].mode = 1; ps.s[1].nValid = L_;
        ps.s[2].A0 = h1cur; ps.s[2].B0 = WqrelSt; ps.s[2].qout = qrelbSt;
        ps.s[2].bias = biasQst + D_; ps.s[2].scale = invs; ps.s[2].mode = 2; ps.s[2].nValid = 256;
        ps.s[3].A0 = h2cur; ps.s[3].B0 = WqrelEd; ps.s[3].qout = qrelbEd;
        ps.s[3].bias = biasQed + D_; ps.s[3].scale = invs; ps.s[3].mode = 2; ps.s[3].nValid = 256;
        k_mfma8<<<dim3(L_ / 256, (B_ * L_) / 256, 4), 512, 0, stream>>>(
            ps, D_, D_, L_, D_, D_, D_, 0, spw, srcm, attm, it);
        // softmax (with rel gather) st+ed
        k_softmax<<<dim3(B_ * L_, 2), 256, 0, stream>>>(
            outSts + (long)it * L_, outEds + (long)it * L_, attn_st, attn_ed,
            qrelbSt, qrelbEd);
    }
}